// Round 3
// baseline (996.066 us; speedup 1.0000x reference)
//
#include <hip/hip_runtime.h>
#include <hip/hip_cooperative_groups.h>
#include <hip/hip_bf16.h>
#include <math.h>

namespace cg = cooperative_groups;

#define HID 128
#define HEADS 8
#define INDIM 64

typedef _Float16 f16x8 __attribute__((ext_vector_type(8)));
typedef _Float16 f16x4 __attribute__((ext_vector_type(4)));
typedef _Float16 f16x2 __attribute__((ext_vector_type(2)));
typedef float f32x4 __attribute__((ext_vector_type(4)));

__device__ __forceinline__ float fast_tanh(float x) {
    return 1.f - 2.f / (__expf(2.f * x) + 1.f);
}

#if defined(__has_builtin)
#if __has_builtin(__builtin_amdgcn_fdot2)
#define HAVE_FDOT2 1
#endif
#endif

// ======================= shared device phase bodies =======================

struct MegaParams {
    const float* x; const int* ei; const int* ntypes; const int* batch;
    const float* emb_W; const float* emb_b; const float* nemb;
    const float* gat_W; const float* att_src; const float* att_dst;
    const float* gat_b; const float* ln_g; const float* ln_b;
    const float* ga_W1; const float* ga_b1; const float* ga_W2; const float* ga_b2;
    const float* cls_W1; const float* cls_b1; const float* cls_W2; const float* cls_b2;
    float* out;
    float *als, *ald, *escore, *sums, *cnts, *hgZ;
    _Float16 *h16, *hp16, *wt_emb, *wt_gat, *wt_ga1;
    int *rowptr, *woff, *deg, *esrc, *partials, *gstart;
    int N, E, EE, G, NB, NT64, P1TOT;
};

// one 64-row tile MFMA projection phase; grid-strides over tiles.
// mode 0: A=f32 x (convert in staging), epilogue bias+ntype_emb -> h16
// mode 1: A=h16, epilogue hp16 + als/ald
// mode 2: A=h16, epilogue tanh MLP -> escore
__device__ __forceinline__ void proj_phase(
    int mode, int K, int N, int NT64,
    const float* __restrict__ Af32, const _Float16* __restrict__ A16,
    const _Float16* __restrict__ Wt,
    const float* __restrict__ bias, const float* __restrict__ nemb,
    const int* __restrict__ ntypes, _Float16* __restrict__ h16out,
    const float* __restrict__ asrc, const float* __restrict__ adst,
    _Float16* __restrict__ hp_out, float* __restrict__ als, float* __restrict__ ald,
    const float* __restrict__ w2, const float* __restrict__ b2,
    float* __restrict__ escore,
    _Float16* w_lds, _Float16* a_lds)
{
    int t = threadIdx.x;
    int KP = K + 8;
    int K8 = K >> 3;

    // stage W once per block (coalesced)
    for (int i = t; i < 128 * K8; i += 256) {
        int row = i / K8, c8 = i - row * K8;
        *(f16x8*)&w_lds[row * KP + 8 * c8] = *(const f16x8*)&Wt[(size_t)row * K + 8 * c8];
    }

    int lane = t & 63, wv = t >> 6;
    int l15 = lane & 15, quad = lane >> 4;

    for (int tile = blockIdx.x; tile < NT64; tile += gridDim.x) {
        int n0 = tile * 64;
        __syncthreads();   // W ready / previous epilogue done with a_lds
        if (mode == 0) {
            for (int i = t; i < 64 * K8; i += 256) {
                int row = i / K8, c8 = i - row * K8;
                f16x8 v = {};
                int n = n0 + row;
                if (n < N) {
                    const float4* ptr = (const float4*)&Af32[(size_t)n * K + 8 * c8];
                    float4 a = ptr[0], b = ptr[1];
                    v[0] = (_Float16)a.x; v[1] = (_Float16)a.y;
                    v[2] = (_Float16)a.z; v[3] = (_Float16)a.w;
                    v[4] = (_Float16)b.x; v[5] = (_Float16)b.y;
                    v[6] = (_Float16)b.z; v[7] = (_Float16)b.w;
                }
                *(f16x8*)&a_lds[row * KP + 8 * c8] = v;
            }
        } else {
            for (int i = t; i < 64 * K8; i += 256) {
                int row = i / K8, c8 = i - row * K8;
                f16x8 v = {};
                if (n0 + row < N) v = *(const f16x8*)&A16[(size_t)(n0 + row) * K + 8 * c8];
                *(f16x8*)&a_lds[row * KP + 8 * c8] = v;
            }
        }
        __syncthreads();

        f32x4 acc[8];
#pragma unroll
        for (int c = 0; c < 8; ++c) acc[c] = (f32x4){0.f, 0.f, 0.f, 0.f};

        int ksteps = K >> 5;
        for (int kk = 0; kk < ksteps; ++kk) {
            f16x8 af = *(const f16x8*)&a_lds[(wv * 16 + l15) * KP + kk * 32 + quad * 8];
#pragma unroll
            for (int c = 0; c < 8; ++c) {
                f16x8 bf = *(const f16x8*)&w_lds[(c * 16 + l15) * KP + kk * 32 + quad * 8];
                acc[c] = __builtin_amdgcn_mfma_f32_16x16x32_f16(af, bf, acc[c], 0, 0, 0);
            }
        }

        // C layout: row = wv*16 + quad*4 + r, col = c*16 + l15
        if (mode == 0) {
            float bv[8];
#pragma unroll
            for (int c = 0; c < 8; ++c) bv[c] = bias[c * 16 + l15];
            __syncthreads();
#pragma unroll
            for (int r = 0; r < 4; ++r) {
                int n = n0 + wv * 16 + quad * 4 + r;
                int nt = (n < N) ? ntypes[n] : 0;
#pragma unroll
                for (int c = 0; c < 8; ++c)
                    a_lds[(wv * 16 + quad * 4 + r) * 136 + c * 16 + l15] =
                        (_Float16)(acc[c][r] + bv[c] + nemb[nt * HID + c * 16 + l15]);
            }
            __syncthreads();
            for (int i = t; i < 64 * 16; i += 256) {
                int row = i >> 4, c8 = i & 15;
                int n = n0 + row;
                if (n < N) *(f16x8*)&h16out[(size_t)n * HID + 8 * c8] = *(const f16x8*)&a_lds[row * 136 + 8 * c8];
            }
        } else if (mode == 1) {
            __syncthreads();
#pragma unroll
            for (int c = 0; c < 8; ++c)
#pragma unroll
                for (int r = 0; r < 4; ++r)
                    a_lds[(wv * 16 + quad * 4 + r) * 136 + c * 16 + l15] = (_Float16)acc[c][r];
            __syncthreads();
            for (int i = t; i < 64 * 16; i += 256) {
                int row = i >> 4, c8 = i & 15;
                int n = n0 + row;
                if (n < N) *(f16x8*)&hp_out[(size_t)n * HID + 8 * c8] = *(const f16x8*)&a_lds[row * 136 + 8 * c8];
            }
            for (int task2 = t; task2 < 512; task2 += 256) {
                int row = task2 >> 3, hd = task2 & 7;
                int n = n0 + row;
                if (n >= N) continue;
                f16x8 v0 = *(const f16x8*)&a_lds[row * 136 + hd * 16];
                f16x8 v1 = *(const f16x8*)&a_lds[row * 136 + hd * 16 + 8];
                float va = 0.f, vd = 0.f;
#pragma unroll
                for (int j = 0; j < 8; ++j) {
                    va += (float)v0[j] * asrc[hd * 16 + j] + (float)v1[j] * asrc[hd * 16 + 8 + j];
                    vd += (float)v0[j] * adst[hd * 16 + j] + (float)v1[j] * adst[hd * 16 + 8 + j];
                }
                als[n * HEADS + hd] = va;
                ald[n * HEADS + hd] = vd;
            }
        } else {
            float b2v = b2[0];
            float treg[4] = {0.f, 0.f, 0.f, 0.f};
#pragma unroll
            for (int c = 0; c < 8; ++c) {
                float b1v = bias[c * 16 + l15];
                float w2v = w2[c * 16 + l15];
#pragma unroll
                for (int r = 0; r < 4; ++r)
                    treg[r] += fast_tanh(acc[c][r] + b1v) * w2v;
            }
#pragma unroll
            for (int r = 0; r < 4; ++r) {
                float v = treg[r];
#pragma unroll
                for (int m = 8; m >= 1; m >>= 1) v += __shfl_xor(v, m, 64);
                if (l15 == 0) {
                    int n = n0 + wv * 16 + quad * 4 + r;
                    if (n < N) escore[n] = __expf(v + b2v);
                }
            }
        }
    }
}

// fused aggregate: wave per node, 16 edges in flight, packed fdot2
__device__ __forceinline__ void agg_phase(
    const int* __restrict__ rowptr, const int* __restrict__ esrc,
    const float* __restrict__ als, const float* __restrict__ ald,
    const _Float16* __restrict__ hp16, const float* __restrict__ gb,
    const float* __restrict__ lg, const float* __restrict__ lb,
    _Float16* __restrict__ h16, int N)
{
    int wave = threadIdx.x >> 6;
    int lane = threadIdx.x & 63;
    int esub = lane >> 4;
    int cg_ = lane & 15;
    int hd = cg_ >> 1;
    int NQ = (N + 3) >> 2;
    for (int q = blockIdx.x; q < NQ; q += gridDim.x) {
        int n = q * 4 + wave;
        if (n >= N) continue;
        float adv = ald[n * HEADS + hd];
        int row = rowptr[n], end = rowptr[n + 1];
        int last = end - 1;
        float acc[8] = {0.f, 0.f, 0.f, 0.f, 0.f, 0.f, 0.f, 0.f};
        float sw = 0.f;
        for (int base = row; base < end; base += 16) {
            int iA = base + esub;
            int iB = iA + 4, iC = iA + 8, iD = iA + 12;
            int cA = iA <= last ? iA : last;
            int cB = iB <= last ? iB : last;
            int cC = iC <= last ? iC : last;
            int cD = iD <= last ? iD : last;
            int sA = esrc[cA], sB = esrc[cB], sC = esrc[cC], sD = esrc[cD];
            f16x8 pA = *(const f16x8*)&hp16[(size_t)sA * HID + cg_ * 8];
            f16x8 pB = *(const f16x8*)&hp16[(size_t)sB * HID + cg_ * 8];
            f16x8 pC = *(const f16x8*)&hp16[(size_t)sC * HID + cg_ * 8];
            f16x8 pD = *(const f16x8*)&hp16[(size_t)sD * HID + cg_ * 8];
            float aA = als[sA * HEADS + hd];
            float aB = als[sB * HEADS + hd];
            float aC = als[sC * HEADS + hd];
            float aD = als[sD * HEADS + hd];
            float lA = aA + adv; lA = lA > 0.f ? lA : 0.2f * lA;
            float lB = aB + adv; lB = lB > 0.f ? lB : 0.2f * lB;
            float lC = aC + adv; lC = lC > 0.f ? lC : 0.2f * lC;
            float lD = aD + adv; lD = lD > 0.f ? lD : 0.2f * lD;
            float wA = __expf(lA) * ((iA < end) ? 1.f : 0.f);
            float wB = __expf(lB) * ((iB < end) ? 1.f : 0.f);
            float wC = __expf(lC) * ((iC < end) ? 1.f : 0.f);
            float wD = __expf(lD) * ((iD < end) ? 1.f : 0.f);
            sw += (wA + wB) + (wC + wD);
#ifdef HAVE_FDOT2
            f16x2 wAB; wAB[0] = (_Float16)wA; wAB[1] = (_Float16)wB;
            f16x2 wCD; wCD[0] = (_Float16)wC; wCD[1] = (_Float16)wD;
#pragma unroll
            for (int j = 0; j < 8; ++j) {
                f16x2 prAB; prAB[0] = pA[j]; prAB[1] = pB[j];
                f16x2 prCD; prCD[0] = pC[j]; prCD[1] = pD[j];
                acc[j] = __builtin_amdgcn_fdot2(prAB, wAB, acc[j], false);
                acc[j] = __builtin_amdgcn_fdot2(prCD, wCD, acc[j], false);
            }
#else
#pragma unroll
            for (int j = 0; j < 8; ++j)
                acc[j] += wA * (float)pA[j] + wB * (float)pB[j]
                        + wC * (float)pC[j] + wD * (float)pD[j];
#endif
        }
#pragma unroll
        for (int m = 16; m <= 32; m <<= 1) {
            sw += __shfl_xor(sw, m, 64);
#pragma unroll
            for (int j = 0; j < 8; ++j) acc[j] += __shfl_xor(acc[j], m, 64);
        }
        float inv_sw = 1.f / sw;
        float4 g0 = ((const float4*)(gb + cg_ * 8))[0];
        float4 g1 = ((const float4*)(gb + cg_ * 8))[1];
        float v[8];
        v[0] = acc[0] * inv_sw + g0.x; v[1] = acc[1] * inv_sw + g0.y;
        v[2] = acc[2] * inv_sw + g0.z; v[3] = acc[3] * inv_sw + g0.w;
        v[4] = acc[4] * inv_sw + g1.x; v[5] = acc[5] * inv_sw + g1.y;
        v[6] = acc[6] * inv_sw + g1.z; v[7] = acc[7] * inv_sw + g1.w;
        float s = 0.f;
#pragma unroll
        for (int j = 0; j < 8; ++j) s += v[j];
#pragma unroll
        for (int m = 32; m >= 1; m >>= 1) s += __shfl_xor(s, m, 64);
        float mu = s * (1.f / 512.f);
        float d[8], sq = 0.f;
#pragma unroll
        for (int j = 0; j < 8; ++j) { d[j] = v[j] - mu; sq += d[j] * d[j]; }
#pragma unroll
        for (int m = 32; m >= 1; m >>= 1) sq += __shfl_xor(sq, m, 64);
        float inv = rsqrtf(sq * (1.f / 512.f) + 1e-5f);
        float4 lg0 = ((const float4*)(lg + cg_ * 8))[0];
        float4 lg1 = ((const float4*)(lg + cg_ * 8))[1];
        float4 lb0 = ((const float4*)(lb + cg_ * 8))[0];
        float4 lb1 = ((const float4*)(lb + cg_ * 8))[1];
        float lgv[8] = {lg0.x, lg0.y, lg0.z, lg0.w, lg1.x, lg1.y, lg1.z, lg1.w};
        float lbv[8] = {lb0.x, lb0.y, lb0.z, lb0.w, lb1.x, lb1.y, lb1.z, lb1.w};
        f16x8 hold = *(const f16x8*)&h16[(size_t)n * HID + cg_ * 8];
        f16x8 hnew;
#pragma unroll
        for (int j = 0; j < 8; ++j) {
            float r = d[j] * inv * lgv[j] + lbv[j] + (float)hold[j];
            hnew[j] = (_Float16)(r > 0.f ? r : 0.f);
        }
        if (esub == 0) *(f16x8*)&h16[(size_t)n * HID + cg_ * 8] = hnew;
    }
}

// ======================= persistent cooperative mega-kernel =======================
__global__ __launch_bounds__(256) void mega_kernel(MegaParams p) {
    __shared__ _Float16 w_lds[128 * 136];   // 34.8 KB
    __shared__ _Float16 a_lds[64 * 136];    // 17.4 KB
    cg::grid_group grid = cg::this_grid();
    int t = threadIdx.x;
    int bid = blockIdx.x, nblk = gridDim.x;

    // ---- P0: zero deg + hgZ ----
    for (int i = bid * 256 + t; i < p.N; i += nblk * 256) p.deg[i] = 0;
    if (bid == 0 && t <= HID) p.hgZ[t] = 0.f;
    grid.sync();

    // ---- P1: deg atomics + weight transposes + gstart ----
    for (int i = bid * 256 + t; i < p.P1TOT; i += nblk * 256) {
        if (i < p.EE) {
            int dst = (i < p.E) ? p.ei[p.E + i] : (i - p.E);
            atomicAdd(&p.deg[dst], 1);
        }
        if (i < 8192) {                       // emb_W [64][128]
            int k = i >> 7, n = i & 127;
            p.wt_emb[n * 64 + k] = (_Float16)p.emb_W[i];
        } else if (i < 8192 + 49152) {        // gat_W [3][128][128]
            int j = i - 8192;
            int l = j >> 14, r = j & 16383;
            int k = r >> 7, n = r & 127;
            p.wt_gat[l * 16384 + n * 128 + k] = (_Float16)p.gat_W[j];
        } else if (i < 73728) {               // ga_W1 [128][128]
            int j = i - 57344;
            int k = j >> 7, n = j & 127;
            p.wt_ga1[n * 128 + k] = (_Float16)p.ga_W1[j];
        }
        if (i >= 100000 && i - 100000 <= p.G) {
            int g = i - 100000;
            int lo = 0, hi = p.N;
            while (lo < hi) {
                int mid = (lo + hi) >> 1;
                if (p.batch[mid] < g) lo = mid + 1; else hi = mid;
            }
            p.gstart[g] = lo;
        }
    }
    grid.sync();

    // ---- P2: emb projection (mode 0) + deg partial sums ----
    proj_phase(0, INDIM, p.N, p.NT64, p.x, nullptr, p.wt_emb, p.emb_b, p.nemb,
               p.ntypes, p.h16, nullptr, nullptr, nullptr, nullptr, nullptr,
               nullptr, nullptr, nullptr, w_lds, a_lds);
    __syncthreads();
    {
        int* itmp2 = (int*)a_lds;
        for (int c = bid; c < p.NB; c += nblk) {
            int i = c * 256 + t;
            int v = (i < p.N) ? p.deg[i] : 0;
#pragma unroll
            for (int m = 32; m >= 1; m >>= 1) v += __shfl_xor(v, m, 64);
            if ((t & 63) == 0) itmp2[t >> 6] = v;
            __syncthreads();
            if (t == 0) p.partials[c] = itmp2[0] + itmp2[1] + itmp2[2] + itmp2[3];
            __syncthreads();
        }
    }
    grid.sync();

    // ---- P2c: rowptr + woff ----
    {
        int* itmp  = (int*)a_lds;
        int* itmp2 = itmp + 256;
        for (int c = bid; c < p.NB; c += nblk) {
            int i = c * 256 + t;
            int v = (i < p.N) ? p.deg[i] : 0;
            int pe = 0;
            for (int j = t; j < c; j += 256) pe += p.partials[j];
#pragma unroll
            for (int m = 32; m >= 1; m >>= 1) pe += __shfl_xor(pe, m, 64);
            itmp[t] = v;
            if ((t & 63) == 0) itmp2[t >> 6] = pe;
            __syncthreads();
#pragma unroll
            for (int off = 1; off < 256; off <<= 1) {
                int xx = (t >= off) ? itmp[t - off] : 0;
                __syncthreads();
                itmp[t] += xx;
                __syncthreads();
            }
            pe = itmp2[0] + itmp2[1] + itmp2[2] + itmp2[3];
            int excl = itmp[t] - v + pe;
            if (i < p.N) { p.rowptr[i] = excl; p.woff[i] = excl; }
            if (c == 0 && t == 0) p.rowptr[p.N] = p.EE;
            __syncthreads();
        }
    }
    grid.sync();

    // ---- P3: layer-0 projection + scatter ----
    proj_phase(1, HID, p.N, p.NT64, nullptr, p.h16, p.wt_gat, nullptr, nullptr,
               nullptr, nullptr, p.att_src, p.att_dst, p.hp16, p.als, p.ald,
               nullptr, nullptr, nullptr, w_lds, a_lds);
    for (int e = bid * 256 + t; e < p.EE; e += nblk * 256) {
        int src, dst;
        if (e < p.E) { src = p.ei[e]; dst = p.ei[p.E + e]; } else { src = dst = e - p.E; }
        int slot = atomicAdd(&p.woff[dst], 1);
        p.esrc[slot] = src;
    }
    grid.sync();

    // ---- P4..P8: aggregate / proj alternation ----
    agg_phase(p.rowptr, p.esrc, p.als, p.ald, p.hp16,
              p.gat_b, p.ln_g, p.ln_b, p.h16, p.N);
    grid.sync();

    for (int l = 1; l < 3; ++l) {
        proj_phase(1, HID, p.N, p.NT64, nullptr, p.h16, p.wt_gat + (size_t)l * HID * HID,
                   nullptr, nullptr, nullptr, nullptr,
                   p.att_src + l * HID, p.att_dst + l * HID,
                   p.hp16, p.als, p.ald, nullptr, nullptr, nullptr, w_lds, a_lds);
        grid.sync();
        agg_phase(p.rowptr, p.esrc, p.als, p.ald, p.hp16,
                  p.gat_b + l * HID, p.ln_g + l * HID, p.ln_b + l * HID, p.h16, p.N);
        grid.sync();
    }

    // ---- P9: score projection (mode 2) ----
    proj_phase(2, HID, p.N, p.NT64, nullptr, p.h16, p.wt_ga1, p.ga_b1, nullptr,
               nullptr, nullptr, nullptr, nullptr, nullptr, nullptr, nullptr,
               p.ga_W2, p.ga_b2, p.escore, w_lds, a_lds);
    grid.sync();

    // ---- P10: pool (block per graph, 2 row-groups) ----
    {
        float* sm = (float*)a_lds;       // 256
        float* sa = sm + 256;            // 256
        float* sz = sa + 256;            // 2
        int c = t & 127, grp = t >> 7;
        for (int g = bid; g < p.G; g += nblk) {
            int s = p.gstart[g], e = p.gstart[g + 1];
            float msum = 0.f, asum = 0.f, z = 0.f;
            for (int n = s + grp; n < e; n += 2) {
                float hv = (float)p.h16[(size_t)n * HID + c];
                float es = p.escore[n];
                msum += hv;
                asum += es * hv;
                if (c == 0) z += es;
            }
            sm[grp * 128 + c] = msum;
            sa[grp * 128 + c] = asum;
            if (c == 0) sz[grp] = z;
            __syncthreads();
            if (t < HID) {
                p.sums[(size_t)g * HID + t] = sm[t] + sm[128 + t];
                atomicAdd(&p.hgZ[t], sa[t] + sa[128 + t]);
            } else if (t == HID) {
                p.cnts[g] = (float)(e - s);
                atomicAdd(&p.hgZ[HID], sz[0] + sz[1]);
            }
            __syncthreads();
        }
    }
    grid.sync();

    // ---- P11: classifier head ----
    {
        float* hr = (float*)a_lds;     // 128
        float* part = hr + 128;        // 2
        for (int g = bid; g < p.G; g += nblk) {
            if (t < HID) {
                float Z = p.hgZ[HID];
                float cnt = p.cnts[g];
                cnt = cnt > 1.f ? cnt : 1.f;
                hr[t] = p.hgZ[t] / Z + p.sums[(size_t)g * HID + t] / cnt;
            }
            __syncthreads();
            if (t < HID) {
                float acc = p.cls_b1[t];
#pragma unroll 8
                for (int k = 0; k < HID; ++k) acc += hr[k] * p.cls_W1[k * HID + t];
                acc = acc > 0.f ? acc : 0.f;
                float v = acc * p.cls_W2[t];
#pragma unroll
                for (int m = 32; m >= 1; m >>= 1) v += __shfl_xor(v, m, 64);
                if ((t & 63) == 0) part[t >> 6] = v;
            }
            __syncthreads();
            if (t == 0) p.out[g] = part[0] + part[1] + p.cls_b2[0];
            __syncthreads();
        }
    }
}

// ======================= fallback multi-kernel path (round-2, verified) =======================

__global__ void prologue_kernel(const int* __restrict__ ei, int* __restrict__ deg,
                                const float* __restrict__ emb_W, const float* __restrict__ gat_W,
                                const float* __restrict__ ga_W1, _Float16* __restrict__ wt_emb,
                                _Float16* __restrict__ wt_gat, _Float16* __restrict__ wt_ga1,
                                const int* __restrict__ batch, int* __restrict__ gstart,
                                float* __restrict__ hgZ,
                                int E, int EE, int N, int G) {
    int i = blockIdx.x * blockDim.x + threadIdx.x;
    if (i < EE) {
        int dst = (i < E) ? ei[E + i] : (i - E);
        atomicAdd(&deg[dst], 1);
    }
    if (i < 8192) {
        int k = i >> 7, n = i & 127;
        wt_emb[n * 64 + k] = (_Float16)emb_W[i];
    } else if (i < 8192 + 49152) {
        int j = i - 8192;
        int l = j >> 14, r = j & 16383;
        int k = r >> 7, n = r & 127;
        wt_gat[l * 16384 + n * 128 + k] = (_Float16)gat_W[j];
    } else if (i < 73728) {
        int j = i - 57344;
        int k = j >> 7, n = j & 127;
        wt_ga1[n * 128 + k] = (_Float16)ga_W1[j];
    } else if (i < 73728 + 129) {
        hgZ[i - 73728] = 0.f;
    }
    if (i >= 100000 && i - 100000 <= G) {
        int g = i - 100000;
        int lo = 0, hi = N;
        while (lo < hi) {
            int mid = (lo + hi) >> 1;
            if (batch[mid] < g) lo = mid + 1; else hi = mid;
        }
        gstart[g] = lo;
    }
}

__global__ __launch_bounds__(256) void mfma_proj_kernel(
    int mode, int K, int N,
    const _Float16* __restrict__ A16, const float* __restrict__ Af32,
    const _Float16* __restrict__ Wt,
    const float* __restrict__ bias, const float* __restrict__ nemb,
    const int* __restrict__ ntypes, _Float16* __restrict__ h16out,
    const float* __restrict__ asrc, const float* __restrict__ adst,
    _Float16* __restrict__ hp_out, float* __restrict__ als, float* __restrict__ ald,
    const float* __restrict__ w2, const float* __restrict__ b2,
    float* __restrict__ escore,
    int PB, int task, const int* __restrict__ ei2,
    const int* __restrict__ degc,
    int* __restrict__ rowptrw, int* __restrict__ woffw, int* __restrict__ esrcw,
    int E2, int EE2)
{
    __shared__ _Float16 w_lds[128 * 136];
    __shared__ _Float16 a_lds[64 * 136];
    int t = threadIdx.x;

    if ((int)blockIdx.x >= PB) {
        if (task == 1) {
            int b = (int)blockIdx.x - PB;
            int i = b * 256 + t;
            int v = (i < N) ? degc[i] : 0;
            int pe = 0;
            for (int j = t; j < (b << 8); j += 256) pe += degc[j];
#pragma unroll
            for (int m = 32; m >= 1; m >>= 1) pe += __shfl_xor(pe, m, 64);
            int* itmp  = (int*)a_lds;
            int* itmp2 = itmp + 256;
            itmp[t] = v;
            if ((t & 63) == 0) itmp2[t >> 6] = pe;
            __syncthreads();
#pragma unroll
            for (int off = 1; off < 256; off <<= 1) {
                int x = (t >= off) ? itmp[t - off] : 0;
                __syncthreads();
                itmp[t] += x;
                __syncthreads();
            }
            pe = itmp2[0] + itmp2[1] + itmp2[2] + itmp2[3];
            int excl = itmp[t] - v + pe;
            if (i < N) { rowptrw[i] = excl; woffw[i] = excl; }
            if (b == 0 && t == 0) rowptrw[N] = EE2;
        } else {
            int sb = (int)blockIdx.x - PB;
            int stride = ((int)gridDim.x - PB) << 8;
            for (int e = sb * 256 + t; e < EE2; e += stride) {
                int src, dst;
                if (e < E2) { src = ei2[e]; dst = ei2[E2 + e]; } else { src = dst = e - E2; }
                int slot = atomicAdd(&woffw[dst], 1);
                esrcw[slot] = src;
            }
        }
        return;
    }

    int KP = K + 8;
    int K8 = K >> 3;
    for (int i = t; i < 128 * K8; i += 256) {
        int row = i / K8, c8 = i - row * K8;
        *(f16x8*)&w_lds[row * KP + 8 * c8] = *(const f16x8*)&Wt[(size_t)row * K + 8 * c8];
    }
    int lane = t & 63, wv = t >> 6;
    int l15 = lane & 15, quad = lane >> 4;

    for (int tile = 0; tile < 2; ++tile) {
        int n0 = blockIdx.x * 128 + tile * 64;
        if (n0 >= N) break;
        __syncthreads();
        if (mode == 0) {
            for (int i = t; i < 64 * K8; i += 256) {
                int row = i / K8, c8 = i - row * K8;
                f16x8 v = {};
                int n = n0 + row;
                if (n < N) {
                    const float4* ptr = (const float4*)&Af32[(size_t)n * K + 8 * c8];
                    float4 a = ptr[0], b = ptr[1];
                    v[0] = (_Float16)a.x; v[1] = (_Float16)a.y;
                    v[2] = (_Float16)a.z; v[3] = (_Float16)a.w;
                    v[4] = (_Float16)b.x; v[5] = (_Float16)b.y;
                    v[6] = (_Float16)b.z; v[7] = (_Float16)b.w;
                }
                *(f16x8*)&a_lds[row * KP + 8 * c8] = v;
            }
        } else {
            for (int i = t; i < 64 * K8; i += 256) {
                int row = i / K8, c8 = i - row * K8;
                f16x8 v = {};
                if (n0 + row < N) v = *(const f16x8*)&A16[(size_t)(n0 + row) * K + 8 * c8];
                *(f16x8*)&a_lds[row * KP + 8 * c8] = v;
            }
        }
        __syncthreads();

        f32x4 acc[8];
#pragma unroll
        for (int c = 0; c < 8; ++c) acc[c] = (f32x4){0.f, 0.f, 0.f, 0.f};
        int ksteps = K >> 5;
        for (int kk = 0; kk < ksteps; ++kk) {
            f16x8 af = *(const f16x8*)&a_lds[(wv * 16 + l15) * KP + kk * 32 + quad * 8];
#pragma unroll
            for (int c = 0; c < 8; ++c) {
                f16x8 bf = *(const f16x8*)&w_lds[(c * 16 + l15) * KP + kk * 32 + quad * 8];
                acc[c] = __builtin_amdgcn_mfma_f32_16x16x32_f16(af, bf, acc[c], 0, 0, 0);
            }
        }

        if (mode == 0) {
            float bv[8];
#pragma unroll
            for (int c = 0; c < 8; ++c) bv[c] = bias[c * 16 + l15];
            __syncthreads();
#pragma unroll
            for (int r = 0; r < 4; ++r) {
                int n = n0 + wv * 16 + quad * 4 + r;
                int nt = (n < N) ? ntypes[n] : 0;
#pragma unroll
                for (int c = 0; c < 8; ++c)
                    a_lds[(wv * 16 + quad * 4 + r) * 136 + c * 16 + l15] =
                        (_Float16)(acc[c][r] + bv[c] + nemb[nt * HID + c * 16 + l15]);
            }
            __syncthreads();
            for (int i = t; i < 64 * 16; i += 256) {
                int row = i >> 4, c8 = i & 15;
                int n = n0 + row;
                if (n < N) *(f16x8*)&h16out[(size_t)n * HID + 8 * c8] = *(const f16x8*)&a_lds[row * 136 + 8 * c8];
            }
        } else if (mode == 1) {
            __syncthreads();
#pragma unroll
            for (int c = 0; c < 8; ++c)
#pragma unroll
                for (int r = 0; r < 4; ++r)
                    a_lds[(wv * 16 + quad * 4 + r) * 136 + c * 16 + l15] = (_Float16)acc[c][r];
            __syncthreads();
            for (int i = t; i < 64 * 16; i += 256) {
                int row = i >> 4, c8 = i & 15;
                int n = n0 + row;
                if (n < N) *(f16x8*)&hp_out[(size_t)n * HID + 8 * c8] = *(const f16x8*)&a_lds[row * 136 + 8 * c8];
            }
            for (int task2 = t; task2 < 512; task2 += 256) {
                int row = task2 >> 3, hd = task2 & 7;
                int n = n0 + row;
                if (n >= N) continue;
                f16x8 v0 = *(const f16x8*)&a_lds[row * 136 + hd * 16];
                f16x8 v1 = *(const f16x8*)&a_lds[row * 136 + hd * 16 + 8];
                float va = 0.f, vd = 0.f;
#pragma unroll
                for (int j = 0; j < 8; ++j) {
                    va += (float)v0[j] * asrc[hd * 16 + j] + (float)v1[j] * asrc[hd * 16 + 8 + j];
                    vd += (float)v0[j] * adst[hd * 16 + j] + (float)v1[j] * adst[hd * 16 + 8 + j];
                }
                als[n * HEADS + hd] = va;
                ald[n * HEADS + hd] = vd;
            }
        } else {
            float b2v = b2[0];
            float treg[4] = {0.f, 0.f, 0.f, 0.f};
#pragma unroll
            for (int c = 0; c < 8; ++c) {
                float b1v = bias[c * 16 + l15];
                float w2v = w2[c * 16 + l15];
#pragma unroll
                for (int r = 0; r < 4; ++r)
                    treg[r] += fast_tanh(acc[c][r] + b1v) * w2v;
            }
#pragma unroll
            for (int r = 0; r < 4; ++r) {
                float v = treg[r];
#pragma unroll
                for (int m = 8; m >= 1; m >>= 1) v += __shfl_xor(v, m, 64);
                if (l15 == 0) {
                    int n = n0 + wv * 16 + quad * 4 + r;
                    if (n < N) escore[n] = __expf(v + b2v);
                }
            }
        }
    }
}

__global__ void gat_aggregate_kernel(const int* __restrict__ rowptr, const int* __restrict__ esrc,
                                     const float* __restrict__ als, const float* __restrict__ ald,
                                     const _Float16* __restrict__ hp16, const float* __restrict__ gb,
                                     const float* __restrict__ lg, const float* __restrict__ lb,
                                     _Float16* __restrict__ h16, int N) {
    agg_phase(rowptr, esrc, als, ald, hp16, gb, lg, lb, h16, N);
}

__global__ void pool_graph_kernel(const _Float16* __restrict__ h16, const float* __restrict__ escore,
                                  const int* __restrict__ gstart, float* __restrict__ sums,
                                  float* __restrict__ cnts, float* __restrict__ hgZ, int G) {
    int g = blockIdx.x;
    int t = threadIdx.x;
    int c = t & 127, grp = t >> 7;
    int s = gstart[g], e = gstart[g + 1];
    float msum = 0.f, asum = 0.f, z = 0.f;
    for (int n = s + grp; n < e; n += 4) {
        float hv = (float)h16[(size_t)n * HID + c];
        float es = escore[n];
        msum += hv;
        asum += es * hv;
        if (c == 0) z += es;
    }
    __shared__ float sm[4][HID];
    __shared__ float sa[4][HID];
    __shared__ float sz[4];
    sm[grp][c] = msum;
    sa[grp][c] = asum;
    if (c == 0) sz[grp] = z;
    __syncthreads();
    if (t < HID) {
        float m = sm[0][t] + sm[1][t] + sm[2][t] + sm[3][t];
        float a = sa[0][t] + sa[1][t] + sa[2][t] + sa[3][t];
        sums[(size_t)g * HID + t] = m;
        atomicAdd(&hgZ[t], a);
    } else if (t == HID) {
        cnts[g] = (float)(e - s);
        atomicAdd(&hgZ[HID], sz[0] + sz[1] + sz[2] + sz[3]);
    }
}

__global__ void head_kernel(const float* __restrict__ hgZ, const float* __restrict__ sums,
                            const float* __restrict__ cnts, const float* __restrict__ W1,
                            const float* __restrict__ b1, const float* __restrict__ W2,
                            const float* __restrict__ b2, float* __restrict__ out, int G) {
    int g = blockIdx.x;
    int t = threadIdx.x;
    __shared__ float hr[HID];
    __shared__ float part[2];
    float Z = hgZ[HID];
    float cnt = cnts[g];
    cnt = cnt > 1.f ? cnt : 1.f;
    hr[t] = hgZ[t] / Z + sums[(size_t)g * HID + t] / cnt;
    __syncthreads();
    float acc = b1[t];
#pragma unroll 8
    for (int k = 0; k < HID; ++k) acc += hr[k] * W1[k * HID + t];
    acc = acc > 0.f ? acc : 0.f;
    float v = acc * W2[t];
#pragma unroll
    for (int m = 32; m >= 1; m >>= 1) v += __shfl_xor(v, m, 64);
    if ((t & 63) == 0) part[t >> 6] = v;
    __syncthreads();
    if (t == 0) out[g] = part[0] + part[1] + b2[0];
}

// ======================= host launch =======================
extern "C" void kernel_launch(void* const* d_in, const int* in_sizes, int n_in,
                              void* d_out, int out_size, void* d_ws, size_t ws_size,
                              hipStream_t stream) {
    const float* x        = (const float*)d_in[0];
    const int*   ei       = (const int*)d_in[1];
    const int*   ntypes   = (const int*)d_in[2];
    const int*   batch    = (const int*)d_in[3];
    const float* emb_W    = (const float*)d_in[4];
    const float* emb_b    = (const float*)d_in[5];
    const float* nemb     = (const float*)d_in[6];
    const float* gat_W    = (const float*)d_in[7];
    const float* att_src  = (const float*)d_in[8];
    const float* att_dst  = (const float*)d_in[9];
    const float* gat_b    = (const float*)d_in[10];
    const float* ln_g     = (const float*)d_in[11];
    const float* ln_b     = (const float*)d_in[12];
    const float* ga_W1    = (const float*)d_in[13];
    const float* ga_b1    = (const float*)d_in[14];
    const float* ga_W2    = (const float*)d_in[15];
    const float* ga_b2    = (const float*)d_in[16];
    const float* cls_W1   = (const float*)d_in[17];
    const float* cls_b1   = (const float*)d_in[18];
    const float* cls_W2   = (const float*)d_in[19];
    const float* cls_b2   = (const float*)d_in[20];
    float* out = (float*)d_out;

    const int N  = in_sizes[2];
    const int E  = in_sizes[1] / 2;
    const int EE = E + N;
    const int G  = out_size;
    const int NB = (N + 255) / 256;

    float* ws      = (float*)d_ws;
    float* als     = ws;
    float* ald     = als + (size_t)N * HEADS;
    float* escore  = ald + (size_t)N * HEADS;
    float* sums    = escore + N;
    float* cnts    = sums + (size_t)G * HID;
    float* hgZ     = cnts + G;
    _Float16* h16  = (_Float16*)(hgZ + HID + 1);
    _Float16* hp16 = h16 + (size_t)N * HID;
    _Float16* wt_emb = hp16 + (size_t)N * HID;
    _Float16* wt_gat = wt_emb + 128 * 64;
    _Float16* wt_ga1 = wt_gat + 3 * 128 * 128;
    int*   rowptr  = (int*)(wt_ga1 + 128 * 128);
    int*   woff    = rowptr + (N + 1);
    int*   deg     = woff + N;
    int*   esrc    = deg + N;
    int*   gstart  = esrc + EE;
    int*   partials= gstart + (G + 2);

    int P1TOT = EE;
    if (P1TOT < 100000 + G + 1) P1TOT = 100000 + G + 1;

    // ---- cooperative mega-kernel (preferred) ----
    static int coop_blocks = -2;   // -2: untested, -1: unsupported, >0: grid size
    if (coop_blocks == -2) {
        int occ = 0;
        hipError_t oe = hipOccupancyMaxActiveBlocksPerMultiprocessor(&occ, mega_kernel, 256, 0);
        if (oe != hipSuccess || occ < 1) coop_blocks = -1;
        else {
            if (occ > 3) occ = 3;
            coop_blocks = occ * 256;
        }
    }

    if (coop_blocks > 0) {
        MegaParams p;
        p.x = x; p.ei = ei; p.ntypes = ntypes; p.batch = batch;
        p.emb_W = emb_W; p.emb_b = emb_b; p.nemb = nemb;
        p.gat_W = gat_W; p.att_src = att_src; p.att_dst = att_dst;
        p.gat_b = gat_b; p.ln_g = ln_g; p.ln_b = ln_b;
        p.ga_W1 = ga_W1; p.ga_b1 = ga_b1; p.ga_W2 = ga_W2; p.ga_b2 = ga_b2;
        p.cls_W1 = cls_W1; p.cls_b1 = cls_b1; p.cls_W2 = cls_W2; p.cls_b2 = cls_b2;
        p.out = out;
        p.als = als; p.ald = ald; p.escore = escore; p.sums = sums; p.cnts = cnts; p.hgZ = hgZ;
        p.h16 = h16; p.hp16 = hp16; p.wt_emb = wt_emb; p.wt_gat = wt_gat; p.wt_ga1 = wt_ga1;
        p.rowptr = rowptr; p.woff = woff; p.deg = deg; p.esrc = esrc;
        p.partials = partials; p.gstart = gstart;
        p.N = N; p.E = E; p.EE = EE; p.G = G; p.NB = NB;
        p.NT64 = (N + 63) / 64; p.P1TOT = P1TOT;
        void* args[] = { &p };
        hipError_t err = hipLaunchCooperativeKernel(mega_kernel, dim3(coop_blocks), dim3(256),
                                                    args, 0, stream);
        if (err == hipSuccess) return;
        coop_blocks = -1;   // remember failure, fall through to multi-kernel path
    }

    // ---- fallback: round-2 multi-kernel chain ----
    hipMemsetAsync(deg, 0, (size_t)N * sizeof(int), stream);
    prologue_kernel<<<(P1TOT + 255) / 256, 256, 0, stream>>>(
        ei, deg, emb_W, gat_W, ga_W1, wt_emb, wt_gat, wt_ga1,
        batch, gstart, hgZ, E, EE, N, G);

    const int PB = (N + 127) / 128;
    int SCB = 768 - PB;
    if (SCB < 128) SCB = 128;

    mfma_proj_kernel<<<PB + NB, 256, 0, stream>>>(
        0, INDIM, N, nullptr, x, wt_emb, emb_b, nemb, ntypes, h16,
        nullptr, nullptr, nullptr, nullptr, nullptr, nullptr, nullptr, nullptr,
        PB, 1, nullptr, deg, rowptr, woff, nullptr, E, EE);

    mfma_proj_kernel<<<PB + SCB, 256, 0, stream>>>(
        1, HID, N, h16, nullptr, wt_gat,
        nullptr, nullptr, nullptr, nullptr,
        att_src, att_dst, hp16, als, ald, nullptr, nullptr, nullptr,
        PB, 2, ei, nullptr, nullptr, woff, esrc, E, EE);

    gat_aggregate_kernel<<<(N + 3) / 4, 256, 0, stream>>>(
        rowptr, esrc, als, ald, hp16,
        gat_b, ln_g, ln_b, h16, N);

    for (int l = 1; l < 3; ++l) {
        mfma_proj_kernel<<<PB, 256, 0, stream>>>(
            1, HID, N, h16, nullptr, wt_gat + (size_t)l * HID * HID,
            nullptr, nullptr, nullptr, nullptr,
            att_src + l * HID, att_dst + l * HID,
            hp16, als, ald, nullptr, nullptr, nullptr,
            PB, 0, nullptr, nullptr, nullptr, nullptr, nullptr, 0, 0);
        gat_aggregate_kernel<<<(N + 3) / 4, 256, 0, stream>>>(
            rowptr, esrc, als, ald, hp16,
            gat_b + l * HID, ln_g + l * HID, ln_b + l * HID, h16, N);
    }

    mfma_proj_kernel<<<PB, 256, 0, stream>>>(
        2, HID, N, h16, nullptr, wt_ga1, ga_b1, nullptr, nullptr, nullptr,
        nullptr, nullptr, nullptr, nullptr, nullptr, ga_W2, ga_b2, escore,
        PB, 0, nullptr, nullptr, nullptr, nullptr, nullptr, 0, 0);

    pool_graph_kernel<<<G, 512, 0, stream>>>(h16, escore, gstart, sums, cnts, hgZ, G);
    head_kernel<<<G, 128, 0, stream>>>(hgZ, sums, cnts, cls_W1, cls_b1, cls_W2, cls_b2, out, G);
}

// Round 4
// 524.063 us; speedup vs baseline: 1.9007x; 1.9007x over previous
//
#include <hip/hip_runtime.h>
#include <hip/hip_bf16.h>
#include <math.h>

#define HID 128
#define HEADS 8
#define INDIM 64

typedef _Float16 f16x8 __attribute__((ext_vector_type(8)));
typedef _Float16 f16x2 __attribute__((ext_vector_type(2)));
typedef float f32x4 __attribute__((ext_vector_type(4)));

__device__ __forceinline__ float fast_tanh(float x) {
    return 1.f - 2.f / (__expf(2.f * x) + 1.f);
}

#if defined(__has_builtin)
#if __has_builtin(__builtin_amdgcn_fdot2)
#define HAVE_FDOT2 1
#endif
#endif

// ================= prologue: deg count + weight transposes + gstart + hgZ zero ==========
__global__ void prologue_kernel(const int* __restrict__ ei, int* __restrict__ deg,
                                const float* __restrict__ emb_W, const float* __restrict__ gat_W,
                                const float* __restrict__ ga_W1, _Float16* __restrict__ wt_emb,
                                _Float16* __restrict__ wt_gat, _Float16* __restrict__ wt_ga1,
                                const int* __restrict__ batch, int* __restrict__ gstart,
                                float* __restrict__ hgZ,
                                int E, int EE, int N, int G) {
    int i = blockIdx.x * blockDim.x + threadIdx.x;
    if (i < EE) {
        int dst = (i < E) ? ei[E + i] : (i - E);
        atomicAdd(&deg[dst], 1);
    }
    if (i < 8192) {                       // emb_W [64][128]
        int k = i >> 7, n = i & 127;
        wt_emb[n * 64 + k] = (_Float16)emb_W[i];
    } else if (i < 8192 + 49152) {        // gat_W [3][128][128]
        int j = i - 8192;
        int l = j >> 14, r = j & 16383;
        int k = r >> 7, n = r & 127;
        wt_gat[l * 16384 + n * 128 + k] = (_Float16)gat_W[j];
    } else if (i < 73728) {               // ga_W1 [128][128]
        int j = i - 57344;
        int k = j >> 7, n = j & 127;
        wt_ga1[n * 128 + k] = (_Float16)ga_W1[j];
    } else if (i < 73728 + 129) {         // hgZ zero
        hgZ[i - 73728] = 0.f;
    }
    if (i >= 100000 && i - 100000 <= G) {
        int g = i - 100000;
        int lo = 0, hi = N;
        while (lo < hi) {
            int mid = (lo + hi) >> 1;
            if (batch[mid] < g) lo = mid + 1; else hi = mid;
        }
        gstart[g] = lo;
    }
}

// ================= FK: fused emb-proj + layer0-proj (node-local chain) =================
// Extra blocks (>= PB): rowptr chunks, then device barrier among the NB extras, then scatter.
// Progress-safe: extras only wait on other extras; MFMA blocks never wait.
__global__ __launch_bounds__(256) void emb_l0_kernel(
    const float* __restrict__ x, const _Float16* __restrict__ wt_emb,
    const float* __restrict__ emb_b, const float* __restrict__ nemb,
    const int* __restrict__ ntypes,
    _Float16* __restrict__ h16,
    const _Float16* __restrict__ wt_g0,
    const float* __restrict__ asrc, const float* __restrict__ adst,
    _Float16* __restrict__ hp_out, float* __restrict__ als_out, float* __restrict__ ald_out,
    int PB, const int* __restrict__ ei, const int* __restrict__ deg,
    int* __restrict__ rowptr, int* __restrict__ woff, int* __restrict__ esrc,
    int* __restrict__ ctr,
    int N, int E, int EE, int NB)
{
    __shared__ _Float16 w_lds[128 * 136];   // 34.8 KB
    __shared__ _Float16 a_lds[64 * 136];    // 17.4 KB
    int t = threadIdx.x;

    if ((int)blockIdx.x >= PB) {
        // ---- rowptr chunk (direct strided prefix over deg, proven in R2) ----
        int b = (int)blockIdx.x - PB;
        int i = b * 256 + t;
        int v = (i < N) ? deg[i] : 0;
        int pe = 0;
        for (int j = t; j < (b << 8); j += 256) pe += deg[j];
#pragma unroll
        for (int m = 32; m >= 1; m >>= 1) pe += __shfl_xor(pe, m, 64);
        int* itmp  = (int*)a_lds;
        int* itmp2 = itmp + 256;
        itmp[t] = v;
        if ((t & 63) == 0) itmp2[t >> 6] = pe;
        __syncthreads();
#pragma unroll
        for (int off = 1; off < 256; off <<= 1) {
            int xx = (t >= off) ? itmp[t - off] : 0;
            __syncthreads();
            itmp[t] += xx;
            __syncthreads();
        }
        pe = itmp2[0] + itmp2[1] + itmp2[2] + itmp2[3];
        int excl = itmp[t] - v + pe;
        if (i < N) { rowptr[i] = excl; woff[i] = excl; }
        if (b == 0 && t == 0) rowptr[N] = EE;
        __threadfence();          // own stores device-visible
        __syncthreads();          // all lanes fenced
        if (t == 0) {
            atomicAdd(ctr, 1);
            while (atomicAdd(ctr, 0) < NB) __builtin_amdgcn_s_sleep(16);
        }
        __syncthreads();
        // ---- scatter (grid-stride over the NB extras) ----
        for (int e = b * 256 + t; e < EE; e += NB * 256) {
            int src, dst;
            if (e < E) { src = ei[e]; dst = ei[E + e]; } else { src = dst = e - E; }
            int slot = atomicAdd(&woff[dst], 1);
            esrc[slot] = src;
        }
        return;
    }

    // ---- emb proj (K=64, KP=72) ----
    for (int i = t; i < 128 * 8; i += 256) {
        int row = i >> 3, c8 = i & 7;
        *(f16x8*)&w_lds[row * 72 + 8 * c8] = *(const f16x8*)&wt_emb[(size_t)row * 64 + 8 * c8];
    }
    int n0 = blockIdx.x * 64;
    for (int i = t; i < 64 * 8; i += 256) {
        int row = i >> 3, c8 = i & 7;
        f16x8 v = {};
        int n = n0 + row;
        if (n < N) {
            const float4* ptr = (const float4*)&x[(size_t)n * 64 + 8 * c8];
            float4 a = ptr[0], b4 = ptr[1];
            v[0] = (_Float16)a.x; v[1] = (_Float16)a.y;
            v[2] = (_Float16)a.z; v[3] = (_Float16)a.w;
            v[4] = (_Float16)b4.x; v[5] = (_Float16)b4.y;
            v[6] = (_Float16)b4.z; v[7] = (_Float16)b4.w;
        }
        *(f16x8*)&a_lds[row * 72 + 8 * c8] = v;
    }
    __syncthreads();

    int lane = t & 63, wv = t >> 6;
    int l15 = lane & 15, quad = lane >> 4;

    f32x4 acc[8];
#pragma unroll
    for (int c = 0; c < 8; ++c) acc[c] = (f32x4){0.f, 0.f, 0.f, 0.f};
#pragma unroll
    for (int kk = 0; kk < 2; ++kk) {
        f16x8 af = *(const f16x8*)&a_lds[(wv * 16 + l15) * 72 + kk * 32 + quad * 8];
#pragma unroll
        for (int c = 0; c < 8; ++c) {
            f16x8 bf = *(const f16x8*)&w_lds[(c * 16 + l15) * 72 + kk * 32 + quad * 8];
            acc[c] = __builtin_amdgcn_mfma_f32_16x16x32_f16(af, bf, acc[c], 0, 0, 0);
        }
    }
    float bv[8];
#pragma unroll
    for (int c = 0; c < 8; ++c) bv[c] = emb_b[c * 16 + l15];
    __syncthreads();   // all MFMA reads of a_lds/w_lds done
    // epilogue: h -> a_lds (stride 136) ; concurrently stage layer-0 W
#pragma unroll
    for (int r = 0; r < 4; ++r) {
        int n = n0 + wv * 16 + quad * 4 + r;
        int nt = (n < N) ? ntypes[n] : 0;
#pragma unroll
        for (int c = 0; c < 8; ++c)
            a_lds[(wv * 16 + quad * 4 + r) * 136 + c * 16 + l15] =
                (_Float16)(acc[c][r] + bv[c] + nemb[nt * HID + c * 16 + l15]);
    }
    for (int i = t; i < 128 * 16; i += 256) {
        int row = i >> 4, c8 = i & 15;
        *(f16x8*)&w_lds[row * 136 + 8 * c8] = *(const f16x8*)&wt_g0[(size_t)row * 128 + 8 * c8];
    }
    __syncthreads();
    // h16 global store (emb output, residual for F1) + layer-0 MFMA
    for (int i = t; i < 64 * 16; i += 256) {
        int row = i >> 4, c8 = i & 15;
        int n = n0 + row;
        if (n < N) *(f16x8*)&h16[(size_t)n * HID + 8 * c8] = *(const f16x8*)&a_lds[row * 136 + 8 * c8];
    }
#pragma unroll
    for (int c = 0; c < 8; ++c) acc[c] = (f32x4){0.f, 0.f, 0.f, 0.f};
#pragma unroll
    for (int kk = 0; kk < 4; ++kk) {
        f16x8 af = *(const f16x8*)&a_lds[(wv * 16 + l15) * 136 + kk * 32 + quad * 8];
#pragma unroll
        for (int c = 0; c < 8; ++c) {
            f16x8 bf = *(const f16x8*)&w_lds[(c * 16 + l15) * 136 + kk * 32 + quad * 8];
            acc[c] = __builtin_amdgcn_mfma_f32_16x16x32_f16(af, bf, acc[c], 0, 0, 0);
        }
    }
    __syncthreads();
#pragma unroll
    for (int c = 0; c < 8; ++c)
#pragma unroll
        for (int r = 0; r < 4; ++r)
            a_lds[(wv * 16 + quad * 4 + r) * 136 + c * 16 + l15] = (_Float16)acc[c][r];
    __syncthreads();
    for (int i = t; i < 64 * 16; i += 256) {
        int row = i >> 4, c8 = i & 15;
        int n = n0 + row;
        if (n < N) *(f16x8*)&hp_out[(size_t)n * HID + 8 * c8] = *(const f16x8*)&a_lds[row * 136 + 8 * c8];
    }
    for (int task2 = t; task2 < 512; task2 += 256) {
        int row = task2 >> 3, hd = task2 & 7;
        int n = n0 + row;
        if (n >= N) continue;
        f16x8 v0 = *(const f16x8*)&a_lds[row * 136 + hd * 16];
        f16x8 v1 = *(const f16x8*)&a_lds[row * 136 + hd * 16 + 8];
        float va = 0.f, vd = 0.f;
#pragma unroll
        for (int j = 0; j < 8; ++j) {
            va += (float)v0[j] * asrc[hd * 16 + j] + (float)v1[j] * asrc[hd * 16 + 8 + j];
            vd += (float)v0[j] * adst[hd * 16 + j] + (float)v1[j] * adst[hd * 16 + 8 + j];
        }
        als_out[n * HEADS + hd] = va;
        ald_out[n * HEADS + hd] = vd;
    }
}

// ================= F: fused aggregate_l + proj_{l+1} (or score proj) =================
// Block owns 64 nodes. Agg phase: wave per node (16 nodes/wave), result straight into LDS.
// Proj phase: MFMA on the LDS tile. hp/als/ald double-buffered across layers (race-free).
__global__ __launch_bounds__(256) void fused_agg_proj_kernel(
    int mode,   // 1: GAT proj epilogue, 2: score epilogue
    const int* __restrict__ rowptr, const int* __restrict__ esrc,
    const float* __restrict__ als_in, const float* __restrict__ ald_in,
    const _Float16* __restrict__ hp_in,
    const float* __restrict__ gb, const float* __restrict__ lg, const float* __restrict__ lb,
    _Float16* __restrict__ h16,
    const _Float16* __restrict__ Wt,
    const float* __restrict__ asrc, const float* __restrict__ adst,
    _Float16* __restrict__ hp_out, float* __restrict__ als_out, float* __restrict__ ald_out,
    const float* __restrict__ b1, const float* __restrict__ w2, const float* __restrict__ b2,
    float* __restrict__ escore, int N)
{
    __shared__ _Float16 w_lds[128 * 136];
    __shared__ _Float16 a_lds[64 * 136];
    int t = threadIdx.x;
    // stage W early — latency hides under agg phase
    for (int i = t; i < 128 * 16; i += 256) {
        int row = i >> 4, c8 = i & 15;
        *(f16x8*)&w_lds[row * 136 + 8 * c8] = *(const f16x8*)&Wt[(size_t)row * 128 + 8 * c8];
    }
    int wave = t >> 6, lane = t & 63;
    int esub = lane >> 4, cg_ = lane & 15, hd = cg_ >> 1;
    int n0 = blockIdx.x * 64;

    for (int it = 0; it < 16; ++it) {
        int n = n0 + wave * 16 + it;
        if (n >= N) break;
        float adv = ald_in[n * HEADS + hd];
        int rs = rowptr[n], re = rowptr[n + 1];
        int last = re - 1;
        float acc[8] = {0.f, 0.f, 0.f, 0.f, 0.f, 0.f, 0.f, 0.f};
        float sw = 0.f;
        for (int base = rs; base < re; base += 16) {
            int iA = base + esub;
            int iB = iA + 4, iC = iA + 8, iD = iA + 12;
            int cA = iA <= last ? iA : last;
            int cB = iB <= last ? iB : last;
            int cC = iC <= last ? iC : last;
            int cD = iD <= last ? iD : last;
            int sA = esrc[cA], sB = esrc[cB], sC = esrc[cC], sD = esrc[cD];
            f16x8 pA = *(const f16x8*)&hp_in[(size_t)sA * HID + cg_ * 8];
            f16x8 pB = *(const f16x8*)&hp_in[(size_t)sB * HID + cg_ * 8];
            f16x8 pC = *(const f16x8*)&hp_in[(size_t)sC * HID + cg_ * 8];
            f16x8 pD = *(const f16x8*)&hp_in[(size_t)sD * HID + cg_ * 8];
            float aA = als_in[sA * HEADS + hd];
            float aB = als_in[sB * HEADS + hd];
            float aC = als_in[sC * HEADS + hd];
            float aD = als_in[sD * HEADS + hd];
            float lA = aA + adv; lA = lA > 0.f ? lA : 0.2f * lA;
            float lB = aB + adv; lB = lB > 0.f ? lB : 0.2f * lB;
            float lC = aC + adv; lC = lC > 0.f ? lC : 0.2f * lC;
            float lD = aD + adv; lD = lD > 0.f ? lD : 0.2f * lD;
            float wA = __expf(lA) * ((iA < re) ? 1.f : 0.f);
            float wB = __expf(lB) * ((iB < re) ? 1.f : 0.f);
            float wC = __expf(lC) * ((iC < re) ? 1.f : 0.f);
            float wD = __expf(lD) * ((iD < re) ? 1.f : 0.f);
            sw += (wA + wB) + (wC + wD);
#ifdef HAVE_FDOT2
            f16x2 wAB; wAB[0] = (_Float16)wA; wAB[1] = (_Float16)wB;
            f16x2 wCD; wCD[0] = (_Float16)wC; wCD[1] = (_Float16)wD;
#pragma unroll
            for (int j = 0; j < 8; ++j) {
                f16x2 prAB; prAB[0] = pA[j]; prAB[1] = pB[j];
                f16x2 prCD; prCD[0] = pC[j]; prCD[1] = pD[j];
                acc[j] = __builtin_amdgcn_fdot2(prAB, wAB, acc[j], false);
                acc[j] = __builtin_amdgcn_fdot2(prCD, wCD, acc[j], false);
            }
#else
#pragma unroll
            for (int j = 0; j < 8; ++j)
                acc[j] += wA * (float)pA[j] + wB * (float)pB[j]
                        + wC * (float)pC[j] + wD * (float)pD[j];
#endif
        }
#pragma unroll
        for (int m = 16; m <= 32; m <<= 1) {
            sw += __shfl_xor(sw, m, 64);
#pragma unroll
            for (int j = 0; j < 8; ++j) acc[j] += __shfl_xor(acc[j], m, 64);
        }
        float inv_sw = 1.f / sw;
        float4 g0 = ((const float4*)(gb + cg_ * 8))[0];
        float4 g1 = ((const float4*)(gb + cg_ * 8))[1];
        float v[8];
        v[0] = acc[0] * inv_sw + g0.x; v[1] = acc[1] * inv_sw + g0.y;
        v[2] = acc[2] * inv_sw + g0.z; v[3] = acc[3] * inv_sw + g0.w;
        v[4] = acc[4] * inv_sw + g1.x; v[5] = acc[5] * inv_sw + g1.y;
        v[6] = acc[6] * inv_sw + g1.z; v[7] = acc[7] * inv_sw + g1.w;
        float s = 0.f;
#pragma unroll
        for (int j = 0; j < 8; ++j) s += v[j];
#pragma unroll
        for (int m = 32; m >= 1; m >>= 1) s += __shfl_xor(s, m, 64);
        float mu = s * (1.f / 512.f);
        float d[8], sq = 0.f;
#pragma unroll
        for (int j = 0; j < 8; ++j) { d[j] = v[j] - mu; sq += d[j] * d[j]; }
#pragma unroll
        for (int m = 32; m >= 1; m >>= 1) sq += __shfl_xor(sq, m, 64);
        float inv = rsqrtf(sq * (1.f / 512.f) + 1e-5f);
        float4 lg0 = ((const float4*)(lg + cg_ * 8))[0];
        float4 lg1 = ((const float4*)(lg + cg_ * 8))[1];
        float4 lb0 = ((const float4*)(lb + cg_ * 8))[0];
        float4 lb1 = ((const float4*)(lb + cg_ * 8))[1];
        float lgv[8] = {lg0.x, lg0.y, lg0.z, lg0.w, lg1.x, lg1.y, lg1.z, lg1.w};
        float lbv[8] = {lb0.x, lb0.y, lb0.z, lb0.w, lb1.x, lb1.y, lb1.z, lb1.w};
        f16x8 hold = *(const f16x8*)&h16[(size_t)n * HID + cg_ * 8];
        f16x8 hnew;
#pragma unroll
        for (int j = 0; j < 8; ++j) {
            float r = d[j] * inv * lgv[j] + lbv[j] + (float)hold[j];
            hnew[j] = (_Float16)(r > 0.f ? r : 0.f);
        }
        if (esub == 0) {
            *(f16x8*)&a_lds[(wave * 16 + it) * 136 + cg_ * 8] = hnew;
            *(f16x8*)&h16[(size_t)n * HID + cg_ * 8] = hnew;
        }
    }
    __syncthreads();

    // ---- proj phase (K=128) on the LDS tile ----
    int l15 = lane & 15, quad = lane >> 4;
    f32x4 pacc[8];
#pragma unroll
    for (int c = 0; c < 8; ++c) pacc[c] = (f32x4){0.f, 0.f, 0.f, 0.f};
#pragma unroll
    for (int kk = 0; kk < 4; ++kk) {
        f16x8 af = *(const f16x8*)&a_lds[(wave * 16 + l15) * 136 + kk * 32 + quad * 8];
#pragma unroll
        for (int c = 0; c < 8; ++c) {
            f16x8 bf = *(const f16x8*)&w_lds[(c * 16 + l15) * 136 + kk * 32 + quad * 8];
            pacc[c] = __builtin_amdgcn_mfma_f32_16x16x32_f16(af, bf, pacc[c], 0, 0, 0);
        }
    }

    if (mode == 1) {
        __syncthreads();
#pragma unroll
        for (int c = 0; c < 8; ++c)
#pragma unroll
            for (int r = 0; r < 4; ++r)
                a_lds[(wave * 16 + quad * 4 + r) * 136 + c * 16 + l15] = (_Float16)pacc[c][r];
        __syncthreads();
        for (int i = t; i < 64 * 16; i += 256) {
            int row = i >> 4, c8 = i & 15;
            int n = n0 + row;
            if (n < N) *(f16x8*)&hp_out[(size_t)n * HID + 8 * c8] = *(const f16x8*)&a_lds[row * 136 + 8 * c8];
        }
        for (int task2 = t; task2 < 512; task2 += 256) {
            int row = task2 >> 3, hh = task2 & 7;
            int n = n0 + row;
            if (n >= N) continue;
            f16x8 v0 = *(const f16x8*)&a_lds[row * 136 + hh * 16];
            f16x8 v1 = *(const f16x8*)&a_lds[row * 136 + hh * 16 + 8];
            float va = 0.f, vd = 0.f;
#pragma unroll
            for (int j = 0; j < 8; ++j) {
                va += (float)v0[j] * asrc[hh * 16 + j] + (float)v1[j] * asrc[hh * 16 + 8 + j];
                vd += (float)v0[j] * adst[hh * 16 + j] + (float)v1[j] * adst[hh * 16 + 8 + j];
            }
            als_out[n * HEADS + hh] = va;
            ald_out[n * HEADS + hh] = vd;
        }
    } else {
        float b2v = b2[0];
        float treg[4] = {0.f, 0.f, 0.f, 0.f};
#pragma unroll
        for (int c = 0; c < 8; ++c) {
            float b1v = b1[c * 16 + l15];
            float w2v = w2[c * 16 + l15];
#pragma unroll
            for (int r = 0; r < 4; ++r)
                treg[r] += fast_tanh(pacc[c][r] + b1v) * w2v;
        }
#pragma unroll
        for (int r = 0; r < 4; ++r) {
            float v = treg[r];
#pragma unroll
            for (int m = 8; m >= 1; m >>= 1) v += __shfl_xor(v, m, 64);
            if (l15 == 0) {
                int n = n0 + wave * 16 + quad * 4 + r;
                if (n < N) escore[n] = __expf(v + b2v);
            }
        }
    }
}

// ================= per-graph pooling (h16) =================
__global__ void pool_graph_kernel(const _Float16* __restrict__ h16, const float* __restrict__ escore,
                                  const int* __restrict__ gstart, float* __restrict__ sums,
                                  float* __restrict__ cnts, float* __restrict__ hgZ, int G) {
    int g = blockIdx.x;
    int t = threadIdx.x;               // 0..511
    int c = t & 127, grp = t >> 7;     // 4 groups
    int s = gstart[g], e = gstart[g + 1];
    float msum = 0.f, asum = 0.f, z = 0.f;
    for (int n = s + grp; n < e; n += 4) {
        float hv = (float)h16[(size_t)n * HID + c];
        float es = escore[n];
        msum += hv;
        asum += es * hv;
        if (c == 0) z += es;
    }
    __shared__ float sm[4][HID];
    __shared__ float sa[4][HID];
    __shared__ float sz[4];
    sm[grp][c] = msum;
    sa[grp][c] = asum;
    if (c == 0) sz[grp] = z;
    __syncthreads();
    if (t < HID) {
        float m = sm[0][t] + sm[1][t] + sm[2][t] + sm[3][t];
        float a = sa[0][t] + sa[1][t] + sa[2][t] + sa[3][t];
        sums[(size_t)g * HID + t] = m;
        atomicAdd(&hgZ[t], a);
    } else if (t == HID) {
        cnts[g] = (float)(e - s);
        atomicAdd(&hgZ[HID], sz[0] + sz[1] + sz[2] + sz[3]);
    }
}

// ================= classifier head =================
__global__ void head_kernel(const float* __restrict__ hgZ, const float* __restrict__ sums,
                            const float* __restrict__ cnts, const float* __restrict__ W1,
                            const float* __restrict__ b1, const float* __restrict__ W2,
                            const float* __restrict__ b2, float* __restrict__ out, int G) {
    int g = blockIdx.x;
    int t = threadIdx.x;
    __shared__ float hr[HID];
    __shared__ float part[2];
    float Z = hgZ[HID];
    float cnt = cnts[g];
    cnt = cnt > 1.f ? cnt : 1.f;
    hr[t] = hgZ[t] / Z + sums[(size_t)g * HID + t] / cnt;
    __syncthreads();
    float acc = b1[t];
#pragma unroll 8
    for (int k = 0; k < HID; ++k) acc += hr[k] * W1[k * HID + t];
    acc = acc > 0.f ? acc : 0.f;
    float v = acc * W2[t];
#pragma unroll
    for (int m = 32; m >= 1; m >>= 1) v += __shfl_xor(v, m, 64);
    if ((t & 63) == 0) part[t >> 6] = v;
    __syncthreads();
    if (t == 0) out[g] = part[0] + part[1] + b2[0];
}

extern "C" void kernel_launch(void* const* d_in, const int* in_sizes, int n_in,
                              void* d_out, int out_size, void* d_ws, size_t ws_size,
                              hipStream_t stream) {
    const float* x        = (const float*)d_in[0];
    const int*   ei       = (const int*)d_in[1];
    const int*   ntypes   = (const int*)d_in[2];
    const int*   batch    = (const int*)d_in[3];
    const float* emb_W    = (const float*)d_in[4];
    const float* emb_b    = (const float*)d_in[5];
    const float* nemb     = (const float*)d_in[6];
    const float* gat_W    = (const float*)d_in[7];
    const float* att_src  = (const float*)d_in[8];
    const float* att_dst  = (const float*)d_in[9];
    const float* gat_b    = (const float*)d_in[10];
    const float* ln_g     = (const float*)d_in[11];
    const float* ln_b     = (const float*)d_in[12];
    const float* ga_W1    = (const float*)d_in[13];
    const float* ga_b1    = (const float*)d_in[14];
    const float* ga_W2    = (const float*)d_in[15];
    const float* ga_b2    = (const float*)d_in[16];
    const float* cls_W1   = (const float*)d_in[17];
    const float* cls_b1   = (const float*)d_in[18];
    const float* cls_W2   = (const float*)d_in[19];
    const float* cls_b2   = (const float*)d_in[20];
    float* out = (float*)d_out;

    const int N  = in_sizes[2];
    const int E  = in_sizes[1] / 2;
    const int EE = E + N;
    const int G  = out_size;
    const int NB = (N + 255) / 256;

    float* ws      = (float*)d_ws;
    float* als_a   = ws;                               // N*8
    float* ald_a   = als_a + (size_t)N * HEADS;        // N*8
    float* als_b   = ald_a + (size_t)N * HEADS;        // N*8
    float* ald_b   = als_b + (size_t)N * HEADS;        // N*8
    float* escore  = ald_b + (size_t)N * HEADS;        // N
    float* sums    = escore + N;                       // G*128
    float* cnts    = sums + (size_t)G * HID;           // G
    float* hgZ     = cnts + G;                         // 129
    _Float16* h16  = (_Float16*)(hgZ + HID + 1);       // N*128
    _Float16* hp_a = h16 + (size_t)N * HID;            // N*128
    _Float16* hp_b = hp_a + (size_t)N * HID;           // N*128
    _Float16* wt_emb = hp_b + (size_t)N * HID;         // 128*64
    _Float16* wt_gat = wt_emb + 128 * 64;              // 3*128*128
    _Float16* wt_ga1 = wt_gat + 3 * 128 * 128;         // 128*128
    int*   rowptr  = (int*)(wt_ga1 + 128 * 128);       // N+1
    int*   woff    = rowptr + (N + 1);                 // N
    int*   deg     = woff + N;                         // N
    int*   ctr     = deg + N;                          // 1 (zeroed with deg)
    int*   esrc    = ctr + 1;                          // EE
    int*   gstart  = esrc + EE;                        // G+1

    int P1TOT = EE;
    if (P1TOT < 100000 + G + 1) P1TOT = 100000 + G + 1;

    // D1: zero deg + ctr (contiguous)
    hipMemsetAsync(deg, 0, ((size_t)N + 1) * sizeof(int), stream);
    // D2: prologue
    prologue_kernel<<<(P1TOT + 255) / 256, 256, 0, stream>>>(
        ei, deg, emb_W, gat_W, ga_W1, wt_emb, wt_gat, wt_ga1,
        batch, gstart, hgZ, E, EE, N, G);

    const int PB = (N + 63) / 64;   // one 64-node tile per block

    // D3: FK = emb proj + layer-0 proj (+ CSR rowptr/scatter in extras)
    emb_l0_kernel<<<PB + NB, 256, 0, stream>>>(
        x, wt_emb, emb_b, nemb, ntypes, h16,
        wt_gat, att_src, att_dst, hp_a, als_a, ald_a,
        PB, ei, deg, rowptr, woff, esrc, ctr, N, E, EE, NB);

    // D4: F1 = agg0 + proj1   (reads _a, writes _b)
    fused_agg_proj_kernel<<<PB, 256, 0, stream>>>(
        1, rowptr, esrc, als_a, ald_a, hp_a,
        gat_b, ln_g, ln_b, h16,
        wt_gat + 16384, att_src + HID, att_dst + HID,
        hp_b, als_b, ald_b,
        nullptr, nullptr, nullptr, nullptr, N);

    // D5: F2 = agg1 + proj2   (reads _b, writes _a)
    fused_agg_proj_kernel<<<PB, 256, 0, stream>>>(
        1, rowptr, esrc, als_b, ald_b, hp_b,
        gat_b + HID, ln_g + HID, ln_b + HID, h16,
        wt_gat + 32768, att_src + 2 * HID, att_dst + 2 * HID,
        hp_a, als_a, ald_a,
        nullptr, nullptr, nullptr, nullptr, N);

    // D6: F3 = agg2 + score proj (reads _a, writes escore)
    fused_agg_proj_kernel<<<PB, 256, 0, stream>>>(
        2, rowptr, esrc, als_a, ald_a, hp_a,
        gat_b + 2 * HID, ln_g + 2 * HID, ln_b + 2 * HID, h16,
        wt_ga1, nullptr, nullptr,
        nullptr, nullptr, nullptr,
        ga_b1, ga_W2, ga_b2, escore, N);

    // D7/D8: pooling + head
    pool_graph_kernel<<<G, 512, 0, stream>>>(h16, escore, gstart, sums, cnts, hgZ, G);
    head_kernel<<<G, 128, 0, stream>>>(hgZ, sums, cnts, cls_W1, cls_b1, cls_W2, cls_b2, out, G);
}

// Round 5
// 484.461 us; speedup vs baseline: 2.0560x; 1.0817x over previous
//
#include <hip/hip_runtime.h>
#include <hip/hip_bf16.h>
#include <math.h>

#define HID 128
#define HEADS 8
#define INDIM 64

typedef _Float16 f16x8 __attribute__((ext_vector_type(8)));
typedef _Float16 f16x2 __attribute__((ext_vector_type(2)));
typedef float f32x4 __attribute__((ext_vector_type(4)));

__device__ __forceinline__ float fast_tanh(float x) {
    return 1.f - 2.f / (__expf(2.f * x) + 1.f);
}

#if defined(__has_builtin)
#if __has_builtin(__builtin_amdgcn_fdot2)
#define HAVE_FDOT2 1
#endif
#endif

// ================= prologue: deg count + weight transposes + gstart + hgZ zero ==========
__global__ void prologue_kernel(const int* __restrict__ ei, int* __restrict__ deg,
                                const float* __restrict__ emb_W, const float* __restrict__ gat_W,
                                const float* __restrict__ ga_W1, _Float16* __restrict__ wt_emb,
                                _Float16* __restrict__ wt_gat, _Float16* __restrict__ wt_ga1,
                                const int* __restrict__ batch, int* __restrict__ gstart,
                                float* __restrict__ hgZ,
                                int E, int EE, int N, int G) {
    int i = blockIdx.x * blockDim.x + threadIdx.x;
    if (i < EE) {
        int dst = (i < E) ? ei[E + i] : (i - E);
        atomicAdd(&deg[dst], 1);
    }
    if (i < 8192) {                       // emb_W [64][128]
        int k = i >> 7, n = i & 127;
        wt_emb[n * 64 + k] = (_Float16)emb_W[i];
    } else if (i < 8192 + 49152) {        // gat_W [3][128][128]
        int j = i - 8192;
        int l = j >> 14, r = j & 16383;
        int k = r >> 7, n = r & 127;
        wt_gat[l * 16384 + n * 128 + k] = (_Float16)gat_W[j];
    } else if (i < 73728) {               // ga_W1 [128][128]
        int j = i - 57344;
        int k = j >> 7, n = j & 127;
        wt_ga1[n * 128 + k] = (_Float16)ga_W1[j];
    } else if (i < 73728 + 129) {         // hgZ zero
        hgZ[i - 73728] = 0.f;
    }
    if (i >= 100000 && i - 100000 <= G) {
        int g = i - 100000;
        int lo = 0, hi = N;
        while (lo < hi) {
            int mid = (lo + hi) >> 1;
            if (batch[mid] < g) lo = mid + 1; else hi = mid;
        }
        gstart[g] = lo;
    }
}

// ================= FK: fused emb-proj + layer0-proj (1 tile / block) =================
// Extra blocks (>= PB): rowptr chunks, device barrier among the NB extras, then scatter.
// Progress-safe: extras only wait on other extras; MFMA blocks never wait. (verified R4)
__global__ __launch_bounds__(256) void emb_l0_kernel(
    const float* __restrict__ x, const _Float16* __restrict__ wt_emb,
    const float* __restrict__ emb_b, const float* __restrict__ nemb,
    const int* __restrict__ ntypes,
    _Float16* __restrict__ h16,
    const _Float16* __restrict__ wt_g0,
    const float* __restrict__ asrc, const float* __restrict__ adst,
    _Float16* __restrict__ hp_out, float* __restrict__ als_out, float* __restrict__ ald_out,
    int PB, const int* __restrict__ ei, const int* __restrict__ deg,
    int* __restrict__ rowptr, int* __restrict__ woff, int* __restrict__ esrc,
    int* __restrict__ ctr,
    int N, int E, int EE, int NB)
{
    __shared__ _Float16 w_lds[128 * 136];   // 34.8 KB
    __shared__ _Float16 a_lds[64 * 136];    // 17.4 KB
    int t = threadIdx.x;

    if ((int)blockIdx.x >= PB) {
        // ---- rowptr chunk (direct strided prefix over deg) ----
        int b = (int)blockIdx.x - PB;
        int i = b * 256 + t;
        int v = (i < N) ? deg[i] : 0;
        int pe = 0;
        for (int j = t; j < (b << 8); j += 256) pe += deg[j];
#pragma unroll
        for (int m = 32; m >= 1; m >>= 1) pe += __shfl_xor(pe, m, 64);
        int* itmp  = (int*)a_lds;
        int* itmp2 = itmp + 256;
        itmp[t] = v;
        if ((t & 63) == 0) itmp2[t >> 6] = pe;
        __syncthreads();
#pragma unroll
        for (int off = 1; off < 256; off <<= 1) {
            int xx = (t >= off) ? itmp[t - off] : 0;
            __syncthreads();
            itmp[t] += xx;
            __syncthreads();
        }
        pe = itmp2[0] + itmp2[1] + itmp2[2] + itmp2[3];
        int excl = itmp[t] - v + pe;
        if (i < N) { rowptr[i] = excl; woff[i] = excl; }
        if (b == 0 && t == 0) rowptr[N] = EE;
        __threadfence();
        __syncthreads();
        if (t == 0) {
            atomicAdd(ctr, 1);
            while (atomicAdd(ctr, 0) < NB) __builtin_amdgcn_s_sleep(16);
        }
        __syncthreads();
        // ---- scatter (grid-stride over the NB extras) ----
        for (int e = b * 256 + t; e < EE; e += NB * 256) {
            int src, dst;
            if (e < E) { src = ei[e]; dst = ei[E + e]; } else { src = dst = e - E; }
            int slot = atomicAdd(&woff[dst], 1);
            esrc[slot] = src;
        }
        return;
    }

    // ---- emb proj (K=64, KP=72) ----
    for (int i = t; i < 128 * 8; i += 256) {
        int row = i >> 3, c8 = i & 7;
        *(f16x8*)&w_lds[row * 72 + 8 * c8] = *(const f16x8*)&wt_emb[(size_t)row * 64 + 8 * c8];
    }
    int n0 = blockIdx.x * 64;
    for (int i = t; i < 64 * 8; i += 256) {
        int row = i >> 3, c8 = i & 7;
        f16x8 v = {};
        int n = n0 + row;
        if (n < N) {
            const float4* ptr = (const float4*)&x[(size_t)n * 64 + 8 * c8];
            float4 a = ptr[0], b4 = ptr[1];
            v[0] = (_Float16)a.x; v[1] = (_Float16)a.y;
            v[2] = (_Float16)a.z; v[3] = (_Float16)a.w;
            v[4] = (_Float16)b4.x; v[5] = (_Float16)b4.y;
            v[6] = (_Float16)b4.z; v[7] = (_Float16)b4.w;
        }
        *(f16x8*)&a_lds[row * 72 + 8 * c8] = v;
    }
    __syncthreads();

    int lane = t & 63, wv = t >> 6;
    int l15 = lane & 15, quad = lane >> 4;

    f32x4 acc[8];
#pragma unroll
    for (int c = 0; c < 8; ++c) acc[c] = (f32x4){0.f, 0.f, 0.f, 0.f};
#pragma unroll
    for (int kk = 0; kk < 2; ++kk) {
        f16x8 af = *(const f16x8*)&a_lds[(wv * 16 + l15) * 72 + kk * 32 + quad * 8];
#pragma unroll
        for (int c = 0; c < 8; ++c) {
            f16x8 bf = *(const f16x8*)&w_lds[(c * 16 + l15) * 72 + kk * 32 + quad * 8];
            acc[c] = __builtin_amdgcn_mfma_f32_16x16x32_f16(af, bf, acc[c], 0, 0, 0);
        }
    }
    float bv[8];
#pragma unroll
    for (int c = 0; c < 8; ++c) bv[c] = emb_b[c * 16 + l15];
    __syncthreads();
    // epilogue: h -> a_lds (stride 136); concurrently stage layer-0 W
#pragma unroll
    for (int r = 0; r < 4; ++r) {
        int n = n0 + wv * 16 + quad * 4 + r;
        int nt = (n < N) ? ntypes[n] : 0;
#pragma unroll
        for (int c = 0; c < 8; ++c)
            a_lds[(wv * 16 + quad * 4 + r) * 136 + c * 16 + l15] =
                (_Float16)(acc[c][r] + bv[c] + nemb[nt * HID + c * 16 + l15]);
    }
    for (int i = t; i < 128 * 16; i += 256) {
        int row = i >> 4, c8 = i & 15;
        *(f16x8*)&w_lds[row * 136 + 8 * c8] = *(const f16x8*)&wt_g0[(size_t)row * 128 + 8 * c8];
    }
    __syncthreads();
    // h16 global store (residual for agg0) + layer-0 MFMA
    for (int i = t; i < 64 * 16; i += 256) {
        int row = i >> 4, c8 = i & 15;
        int n = n0 + row;
        if (n < N) *(f16x8*)&h16[(size_t)n * HID + 8 * c8] = *(const f16x8*)&a_lds[row * 136 + 8 * c8];
    }
#pragma unroll
    for (int c = 0; c < 8; ++c) acc[c] = (f32x4){0.f, 0.f, 0.f, 0.f};
#pragma unroll
    for (int kk = 0; kk < 4; ++kk) {
        f16x8 af = *(const f16x8*)&a_lds[(wv * 16 + l15) * 136 + kk * 32 + quad * 8];
#pragma unroll
        for (int c = 0; c < 8; ++c) {
            f16x8 bf = *(const f16x8*)&w_lds[(c * 16 + l15) * 136 + kk * 32 + quad * 8];
            acc[c] = __builtin_amdgcn_mfma_f32_16x16x32_f16(af, bf, acc[c], 0, 0, 0);
        }
    }
    __syncthreads();
#pragma unroll
    for (int c = 0; c < 8; ++c)
#pragma unroll
        for (int r = 0; r < 4; ++r)
            a_lds[(wv * 16 + quad * 4 + r) * 136 + c * 16 + l15] = (_Float16)acc[c][r];
    __syncthreads();
    for (int i = t; i < 64 * 16; i += 256) {
        int row = i >> 4, c8 = i & 15;
        int n = n0 + row;
        if (n < N) *(f16x8*)&hp_out[(size_t)n * HID + 8 * c8] = *(const f16x8*)&a_lds[row * 136 + 8 * c8];
    }
    for (int task2 = t; task2 < 512; task2 += 256) {
        int row = task2 >> 3, hd = task2 & 7;
        int n = n0 + row;
        if (n >= N) continue;
        f16x8 v0 = *(const f16x8*)&a_lds[row * 136 + hd * 16];
        f16x8 v1 = *(const f16x8*)&a_lds[row * 136 + hd * 16 + 8];
        float va = 0.f, vd = 0.f;
#pragma unroll
        for (int j = 0; j < 8; ++j) {
            va += (float)v0[j] * asrc[hd * 16 + j] + (float)v1[j] * asrc[hd * 16 + 8 + j];
            vd += (float)v0[j] * adst[hd * 16 + j] + (float)v1[j] * adst[hd * 16 + 8 + j];
        }
        als_out[n * HEADS + hd] = va;
        ald_out[n * HEADS + hd] = vd;
    }
}

// ================= standalone MFMA projection (1 tile of 64 rows per block) ===========
// mode 1: GAT proj epilogue (hp16 store + als/ald via LDS transpose)
// mode 2: score epilogue (tanh MLP -> escore)
__global__ __launch_bounds__(256) void proj_kernel(
    int mode, const _Float16* __restrict__ A16, const _Float16* __restrict__ Wt,
    const float* __restrict__ asrc, const float* __restrict__ adst,
    _Float16* __restrict__ hp_out, float* __restrict__ als, float* __restrict__ ald,
    const float* __restrict__ b1, const float* __restrict__ w2, const float* __restrict__ b2,
    float* __restrict__ escore, int N)
{
    __shared__ _Float16 w_lds[128 * 136];
    __shared__ _Float16 a_lds[64 * 136];
    int t = threadIdx.x;

    for (int i = t; i < 128 * 16; i += 256) {
        int row = i >> 4, c8 = i & 15;
        *(f16x8*)&w_lds[row * 136 + 8 * c8] = *(const f16x8*)&Wt[(size_t)row * 128 + 8 * c8];
    }
    int n0 = blockIdx.x * 64;
    for (int i = t; i < 64 * 16; i += 256) {
        int row = i >> 4, c8 = i & 15;
        f16x8 v = {};
        if (n0 + row < N) v = *(const f16x8*)&A16[(size_t)(n0 + row) * HID + 8 * c8];
        *(f16x8*)&a_lds[row * 136 + 8 * c8] = v;
    }
    __syncthreads();

    int lane = t & 63, wv = t >> 6;
    int l15 = lane & 15, quad = lane >> 4;

    f32x4 acc[8];
#pragma unroll
    for (int c = 0; c < 8; ++c) acc[c] = (f32x4){0.f, 0.f, 0.f, 0.f};
#pragma unroll
    for (int kk = 0; kk < 4; ++kk) {
        f16x8 af = *(const f16x8*)&a_lds[(wv * 16 + l15) * 136 + kk * 32 + quad * 8];
#pragma unroll
        for (int c = 0; c < 8; ++c) {
            f16x8 bf = *(const f16x8*)&w_lds[(c * 16 + l15) * 136 + kk * 32 + quad * 8];
            acc[c] = __builtin_amdgcn_mfma_f32_16x16x32_f16(af, bf, acc[c], 0, 0, 0);
        }
    }

    if (mode == 1) {
        __syncthreads();
#pragma unroll
        for (int c = 0; c < 8; ++c)
#pragma unroll
            for (int r = 0; r < 4; ++r)
                a_lds[(wv * 16 + quad * 4 + r) * 136 + c * 16 + l15] = (_Float16)acc[c][r];
        __syncthreads();
        for (int i = t; i < 64 * 16; i += 256) {
            int row = i >> 4, c8 = i & 15;
            int n = n0 + row;
            if (n < N) *(f16x8*)&hp_out[(size_t)n * HID + 8 * c8] = *(const f16x8*)&a_lds[row * 136 + 8 * c8];
        }
        for (int task2 = t; task2 < 512; task2 += 256) {
            int row = task2 >> 3, hd = task2 & 7;
            int n = n0 + row;
            if (n >= N) continue;
            f16x8 v0 = *(const f16x8*)&a_lds[row * 136 + hd * 16];
            f16x8 v1 = *(const f16x8*)&a_lds[row * 136 + hd * 16 + 8];
            float va = 0.f, vd = 0.f;
#pragma unroll
            for (int j = 0; j < 8; ++j) {
                va += (float)v0[j] * asrc[hd * 16 + j] + (float)v1[j] * asrc[hd * 16 + 8 + j];
                vd += (float)v0[j] * adst[hd * 16 + j] + (float)v1[j] * adst[hd * 16 + 8 + j];
            }
            als[n * HEADS + hd] = va;
            ald[n * HEADS + hd] = vd;
        }
    } else {
        float b2v = b2[0];
        float treg[4] = {0.f, 0.f, 0.f, 0.f};
#pragma unroll
        for (int c = 0; c < 8; ++c) {
            float b1v = b1[c * 16 + l15];
            float w2v = w2[c * 16 + l15];
#pragma unroll
            for (int r = 0; r < 4; ++r)
                treg[r] += fast_tanh(acc[c][r] + b1v) * w2v;
        }
#pragma unroll
        for (int r = 0; r < 4; ++r) {
            float v = treg[r];
#pragma unroll
            for (int m = 8; m >= 1; m >>= 1) v += __shfl_xor(v, m, 64);
            if (l15 == 0) {
                int n = n0 + wv * 16 + quad * 4 + r;
                if (n < N) escore[n] = __expf(v + b2v);
            }
        }
    }
}

// ================= fused aggregate (R2-verified): wave per node, 16 edges in flight ====
__global__ void gat_aggregate_kernel(const int* __restrict__ rowptr, const int* __restrict__ esrc,
                                     const float* __restrict__ als, const float* __restrict__ ald,
                                     const _Float16* __restrict__ hp16, const float* __restrict__ gb,
                                     const float* __restrict__ lg, const float* __restrict__ lb,
                                     _Float16* __restrict__ h16, int N) {
    int wave = threadIdx.x >> 6;
    int lane = threadIdx.x & 63;
    int n = blockIdx.x * 4 + wave;
    if (n >= N) return;
    int esub = lane >> 4;
    int cg = lane & 15;
    int hd = cg >> 1;
    float adv = ald[n * HEADS + hd];
    int row = rowptr[n], end = rowptr[n + 1];
    int last = end - 1;
    float acc[8] = {0.f, 0.f, 0.f, 0.f, 0.f, 0.f, 0.f, 0.f};
    float sw = 0.f;
    for (int base = row; base < end; base += 16) {
        int iA = base + esub;
        int iB = iA + 4, iC = iA + 8, iD = iA + 12;
        int cA = iA <= last ? iA : last;
        int cB = iB <= last ? iB : last;
        int cC = iC <= last ? iC : last;
        int cD = iD <= last ? iD : last;
        int sA = esrc[cA], sB = esrc[cB], sC = esrc[cC], sD = esrc[cD];
        f16x8 pA = *(const f16x8*)&hp16[(size_t)sA * HID + cg * 8];
        f16x8 pB = *(const f16x8*)&hp16[(size_t)sB * HID + cg * 8];
        f16x8 pC = *(const f16x8*)&hp16[(size_t)sC * HID + cg * 8];
        f16x8 pD = *(const f16x8*)&hp16[(size_t)sD * HID + cg * 8];
        float aA = als[sA * HEADS + hd];
        float aB = als[sB * HEADS + hd];
        float aC = als[sC * HEADS + hd];
        float aD = als[sD * HEADS + hd];
        float lA = aA + adv; lA = lA > 0.f ? lA : 0.2f * lA;
        float lB = aB + adv; lB = lB > 0.f ? lB : 0.2f * lB;
        float lC = aC + adv; lC = lC > 0.f ? lC : 0.2f * lC;
        float lD = aD + adv; lD = lD > 0.f ? lD : 0.2f * lD;
        float wA = __expf(lA) * ((iA < end) ? 1.f : 0.f);
        float wB = __expf(lB) * ((iB < end) ? 1.f : 0.f);
        float wC = __expf(lC) * ((iC < end) ? 1.f : 0.f);
        float wD = __expf(lD) * ((iD < end) ? 1.f : 0.f);
        sw += (wA + wB) + (wC + wD);
#ifdef HAVE_FDOT2
        f16x2 wAB; wAB[0] = (_Float16)wA; wAB[1] = (_Float16)wB;
        f16x2 wCD; wCD[0] = (_Float16)wC; wCD[1] = (_Float16)wD;
#pragma unroll
        for (int j = 0; j < 8; ++j) {
            f16x2 prAB; prAB[0] = pA[j]; prAB[1] = pB[j];
            f16x2 prCD; prCD[0] = pC[j]; prCD[1] = pD[j];
            acc[j] = __builtin_amdgcn_fdot2(prAB, wAB, acc[j], false);
            acc[j] = __builtin_amdgcn_fdot2(prCD, wCD, acc[j], false);
        }
#else
#pragma unroll
        for (int j = 0; j < 8; ++j)
            acc[j] += wA * (float)pA[j] + wB * (float)pB[j]
                    + wC * (float)pC[j] + wD * (float)pD[j];
#endif
    }
#pragma unroll
    for (int m = 16; m <= 32; m <<= 1) {
        sw += __shfl_xor(sw, m, 64);
#pragma unroll
        for (int j = 0; j < 8; ++j) acc[j] += __shfl_xor(acc[j], m, 64);
    }
    float inv_sw = 1.f / sw;
    float4 g0 = ((const float4*)(gb + cg * 8))[0];
    float4 g1 = ((const float4*)(gb + cg * 8))[1];
    float v[8];
    v[0] = acc[0] * inv_sw + g0.x; v[1] = acc[1] * inv_sw + g0.y;
    v[2] = acc[2] * inv_sw + g0.z; v[3] = acc[3] * inv_sw + g0.w;
    v[4] = acc[4] * inv_sw + g1.x; v[5] = acc[5] * inv_sw + g1.y;
    v[6] = acc[6] * inv_sw + g1.z; v[7] = acc[7] * inv_sw + g1.w;
    float s = 0.f;
#pragma unroll
    for (int j = 0; j < 8; ++j) s += v[j];
#pragma unroll
    for (int m = 32; m >= 1; m >>= 1) s += __shfl_xor(s, m, 64);
    float mu = s * (1.f / 512.f);
    float d[8], sq = 0.f;
#pragma unroll
    for (int j = 0; j < 8; ++j) { d[j] = v[j] - mu; sq += d[j] * d[j]; }
#pragma unroll
    for (int m = 32; m >= 1; m >>= 1) sq += __shfl_xor(sq, m, 64);
    float inv = rsqrtf(sq * (1.f / 512.f) + 1e-5f);
    float4 lg0 = ((const float4*)(lg + cg * 8))[0];
    float4 lg1 = ((const float4*)(lg + cg * 8))[1];
    float4 lb0 = ((const float4*)(lb + cg * 8))[0];
    float4 lb1 = ((const float4*)(lb + cg * 8))[1];
    float lgv[8] = {lg0.x, lg0.y, lg0.z, lg0.w, lg1.x, lg1.y, lg1.z, lg1.w};
    float lbv[8] = {lb0.x, lb0.y, lb0.z, lb0.w, lb1.x, lb1.y, lb1.z, lb1.w};
    f16x8 hold = *(const f16x8*)&h16[(size_t)n * HID + cg * 8];
    f16x8 hnew;
#pragma unroll
    for (int j = 0; j < 8; ++j) {
        float r = d[j] * inv * lgv[j] + lbv[j] + (float)hold[j];
        hnew[j] = (_Float16)(r > 0.f ? r : 0.f);
    }
    if (esub == 0) *(f16x8*)&h16[(size_t)n * HID + cg * 8] = hnew;
}

// ================= fused pool + head (arrive-and-spin over G co-resident blocks) =======
__global__ __launch_bounds__(256) void pool_head_kernel(
    const _Float16* __restrict__ h16, const float* __restrict__ escore,
    const int* __restrict__ gstart,
    const float* __restrict__ W1, const float* __restrict__ b1,
    const float* __restrict__ W2, const float* __restrict__ b2,
    float* __restrict__ hgZ, int* __restrict__ ctr2,
    float* __restrict__ out, int G)
{
    int g = blockIdx.x;
    int t = threadIdx.x;               // 0..255
    int c = t & 127, grp = t >> 7;     // 2 row groups
    int s = gstart[g], e = gstart[g + 1];
    float msum = 0.f, asum = 0.f, z = 0.f;
    for (int n = s + grp; n < e; n += 2) {
        float hv = (float)h16[(size_t)n * HID + c];
        float es = escore[n];
        msum += hv;
        asum += es * hv;
        if (c == 0) z += es;
    }
    __shared__ float sm[2][HID];
    __shared__ float sa[2][HID];
    __shared__ float szs[2];
    __shared__ float hr[HID];
    __shared__ float part[2];
    sm[grp][c] = msum;
    sa[grp][c] = asum;
    if (c == 0) szs[grp] = z;
    __syncthreads();
    if (t < HID) atomicAdd(&hgZ[t], sa[0][t] + sa[1][t]);
    else if (t == HID) atomicAdd(&hgZ[HID], szs[0] + szs[1]);
    __threadfence();
    __syncthreads();
    if (t == 0) {   // all G blocks co-resident (500 x 256 threads) -> spin is progress-safe
        atomicAdd(ctr2, 1);
        while (atomicAdd(ctr2, 0) < G) __builtin_amdgcn_s_sleep(16);
    }
    __syncthreads();
    // head
    float cnt = (float)(e - s);
    cnt = cnt > 1.f ? cnt : 1.f;
    if (t < HID) {
        float Z = hgZ[HID];
        hr[t] = hgZ[t] / Z + (sm[0][t] + sm[1][t]) / cnt;
    }
    __syncthreads();
    if (t < HID) {
        float acc = b1[t];
#pragma unroll 8
        for (int k = 0; k < HID; ++k) acc += hr[k] * W1[k * HID + t];
        acc = acc > 0.f ? acc : 0.f;
        float v = acc * W2[t];
#pragma unroll
        for (int m = 32; m >= 1; m >>= 1) v += __shfl_xor(v, m, 64);
        if ((t & 63) == 0) part[t >> 6] = v;
    }
    __syncthreads();
    if (t == 0) out[g] = part[0] + part[1] + b2[0];
}

extern "C" void kernel_launch(void* const* d_in, const int* in_sizes, int n_in,
                              void* d_out, int out_size, void* d_ws, size_t ws_size,
                              hipStream_t stream) {
    const float* x        = (const float*)d_in[0];
    const int*   ei       = (const int*)d_in[1];
    const int*   ntypes   = (const int*)d_in[2];
    const int*   batch    = (const int*)d_in[3];
    const float* emb_W    = (const float*)d_in[4];
    const float* emb_b    = (const float*)d_in[5];
    const float* nemb     = (const float*)d_in[6];
    const float* gat_W    = (const float*)d_in[7];
    const float* att_src  = (const float*)d_in[8];
    const float* att_dst  = (const float*)d_in[9];
    const float* gat_b    = (const float*)d_in[10];
    const float* ln_g     = (const float*)d_in[11];
    const float* ln_b     = (const float*)d_in[12];
    const float* ga_W1    = (const float*)d_in[13];
    const float* ga_b1    = (const float*)d_in[14];
    const float* ga_W2    = (const float*)d_in[15];
    const float* ga_b2    = (const float*)d_in[16];
    const float* cls_W1   = (const float*)d_in[17];
    const float* cls_b1   = (const float*)d_in[18];
    const float* cls_W2   = (const float*)d_in[19];
    const float* cls_b2   = (const float*)d_in[20];
    float* out = (float*)d_out;

    const int N  = in_sizes[2];
    const int E  = in_sizes[1] / 2;
    const int EE = E + N;
    const int G  = out_size;
    const int NB = (N + 255) / 256;

    // ---- workspace layout (h16 16B-aligned: 800000 + 50000 + 136 = 850136 words) ----
    float* ws      = (float*)d_ws;
    float* als     = ws;                               // N*8
    float* ald     = als + (size_t)N * HEADS;          // N*8
    float* escore  = ald + (size_t)N * HEADS;          // N
    float* hgZ     = escore + N;                       // 136 (129 used)
    _Float16* h16  = (_Float16*)(hgZ + 136);           // N*128
    _Float16* hp16 = h16 + (size_t)N * HID;            // N*128
    _Float16* wt_emb = hp16 + (size_t)N * HID;         // 128*64
    _Float16* wt_gat = wt_emb + 128 * 64;              // 3*128*128
    _Float16* wt_ga1 = wt_gat + 3 * 128 * 128;         // 128*128
    int*   rowptr  = (int*)(wt_ga1 + 128 * 128);       // N+1
    int*   woff    = rowptr + (N + 1);                 // N
    int*   deg     = woff + N;                         // N
    int*   ctr     = deg + N;                          // 1
    int*   ctr2    = ctr + 1;                          // 1
    int*   esrc    = ctr2 + 1;                         // EE
    int*   gstart  = esrc + EE;                        // G+1

    int P1TOT = EE;
    if (P1TOT < 100000 + G + 1) P1TOT = 100000 + G + 1;

    // D1: zero deg + ctr + ctr2 (contiguous)
    hipMemsetAsync(deg, 0, ((size_t)N + 2) * sizeof(int), stream);
    // D2: prologue
    prologue_kernel<<<(P1TOT + 255) / 256, 256, 0, stream>>>(
        ei, deg, emb_W, gat_W, ga_W1, wt_emb, wt_gat, wt_ga1,
        batch, gstart, hgZ, E, EE, N, G);

    const int PB = (N + 63) / 64;   // 1 tile of 64 rows per block

    // D3: FK = emb proj + layer-0 proj (+ CSR rowptr/scatter in extras)
    emb_l0_kernel<<<PB + NB, 256, 0, stream>>>(
        x, wt_emb, emb_b, nemb, ntypes, h16,
        wt_gat, att_src, att_dst, hp16, als, ald,
        PB, ei, deg, rowptr, woff, esrc, ctr, N, E, EE, NB);

    // D4..D8: agg / proj alternation
    gat_aggregate_kernel<<<(N + 3) / 4, 256, 0, stream>>>(
        rowptr, esrc, als, ald, hp16,
        gat_b, ln_g, ln_b, h16, N);

    for (int l = 1; l < 3; ++l) {
        proj_kernel<<<PB, 256, 0, stream>>>(
            1, h16, wt_gat + (size_t)l * HID * HID,
            att_src + l * HID, att_dst + l * HID,
            hp16, als, ald, nullptr, nullptr, nullptr, nullptr, N);
        gat_aggregate_kernel<<<(N + 3) / 4, 256, 0, stream>>>(
            rowptr, esrc, als, ald, hp16,
            gat_b + l * HID, ln_g + l * HID, ln_b + l * HID, h16, N);
    }

    // D9: score projection
    proj_kernel<<<PB, 256, 0, stream>>>(
        2, h16, wt_ga1, nullptr, nullptr,
        nullptr, nullptr, nullptr,
        ga_b1, ga_W2, ga_b2, escore, N);

    // D10: fused pool + head
    pool_head_kernel<<<G, 256, 0, stream>>>(
        h16, escore, gstart, cls_W1, cls_b1, cls_W2, cls_b2,
        hgZ, ctr2, out, G);
}

// Round 6
// 415.983 us; speedup vs baseline: 2.3945x; 1.1646x over previous
//
#include <hip/hip_runtime.h>
#include <hip/hip_bf16.h>
#include <math.h>

#define HID 128
#define HEADS 8
#define INDIM 64

typedef _Float16 f16x8 __attribute__((ext_vector_type(8)));
typedef _Float16 f16x2 __attribute__((ext_vector_type(2)));
typedef float f32x4 __attribute__((ext_vector_type(4)));

__device__ __forceinline__ float fast_tanh(float x) {
    return 1.f - 2.f / (__expf(2.f * x) + 1.f);
}

#if defined(__has_builtin)
#if __has_builtin(__builtin_amdgcn_fdot2)
#define HAVE_FDOT2 1
#endif
#endif

// ================= prologue: deg count + weight transposes + gstart + hgZ zero ==========
__global__ void prologue_kernel(const int* __restrict__ ei, int* __restrict__ deg,
                                const float* __restrict__ emb_W, const float* __restrict__ gat_W,
                                const float* __restrict__ ga_W1, _Float16* __restrict__ wt_emb,
                                _Float16* __restrict__ wt_gat, _Float16* __restrict__ wt_ga1,
                                const int* __restrict__ batch, int* __restrict__ gstart,
                                float* __restrict__ hgZ,
                                int E, int EE, int N, int G) {
    int i = blockIdx.x * blockDim.x + threadIdx.x;
    if (i < EE) {
        int dst = (i < E) ? ei[E + i] : (i - E);
        atomicAdd(&deg[dst], 1);
    }
    if (i < 8192) {                       // emb_W [64][128]
        int k = i >> 7, n = i & 127;
        wt_emb[n * 64 + k] = (_Float16)emb_W[i];
    } else if (i < 8192 + 49152) {        // gat_W [3][128][128]
        int j = i - 8192;
        int l = j >> 14, r = j & 16383;
        int k = r >> 7, n = r & 127;
        wt_gat[l * 16384 + n * 128 + k] = (_Float16)gat_W[j];
    } else if (i < 73728) {               // ga_W1 [128][128]
        int j = i - 57344;
        int k = j >> 7, n = j & 127;
        wt_ga1[n * 128 + k] = (_Float16)ga_W1[j];
    } else if (i < 73728 + 129) {         // hgZ zero
        hgZ[i - 73728] = 0.f;
    }
    if (i >= 100000 && i - 100000 <= G) {
        int g = i - 100000;
        int lo = 0, hi = N;
        while (lo < hi) {
            int mid = (lo + hi) >> 1;
            if (batch[mid] < g) lo = mid + 1; else hi = mid;
        }
        gstart[g] = lo;
    }
}

// ================= FK: fused emb-proj + layer0-proj (1 tile / block) =================
// CSR extras at LOW block IDs (0..NB-1): dispatched first -> co-resident from t=0, so
// rowptr + scatter overlap the MFMA blocks (R5 put them at high IDs past the 768-block
// co-residency limit -> fully serialized, 97 us). MFMA tiles at blocks NB..NB+PB-1.
__global__ __launch_bounds__(256) void emb_l0_kernel(
    const float* __restrict__ x, const _Float16* __restrict__ wt_emb,
    const float* __restrict__ emb_b, const float* __restrict__ nemb,
    const int* __restrict__ ntypes,
    _Float16* __restrict__ h16,
    const _Float16* __restrict__ wt_g0,
    const float* __restrict__ asrc, const float* __restrict__ adst,
    _Float16* __restrict__ hp_out, float* __restrict__ als_out, float* __restrict__ ald_out,
    const int* __restrict__ ei, const int* __restrict__ deg,
    int* __restrict__ rowptr, int* __restrict__ woff, int* __restrict__ esrc,
    int* __restrict__ ctr,
    int N, int E, int EE, int NB)
{
    __shared__ _Float16 w_lds[128 * 136];   // 34.8 KB
    __shared__ _Float16 a_lds[64 * 136];    // 17.4 KB
    int t = threadIdx.x;

    if ((int)blockIdx.x < NB) {
        // ---- rowptr chunk (direct strided prefix over deg) ----
        int b = (int)blockIdx.x;
        int i = b * 256 + t;
        int v = (i < N) ? deg[i] : 0;
        int pe = 0;
        for (int j = t; j < (b << 8); j += 256) pe += deg[j];
#pragma unroll
        for (int m = 32; m >= 1; m >>= 1) pe += __shfl_xor(pe, m, 64);
        int* itmp  = (int*)a_lds;
        int* itmp2 = itmp + 256;
        itmp[t] = v;
        if ((t & 63) == 0) itmp2[t >> 6] = pe;
        __syncthreads();
#pragma unroll
        for (int off = 1; off < 256; off <<= 1) {
            int xx = (t >= off) ? itmp[t - off] : 0;
            __syncthreads();
            itmp[t] += xx;
            __syncthreads();
        }
        pe = itmp2[0] + itmp2[1] + itmp2[2] + itmp2[3];
        int excl = itmp[t] - v + pe;
        if (i < N) { rowptr[i] = excl; woff[i] = excl; }
        if (b == 0 && t == 0) rowptr[N] = EE;
        __threadfence();
        __syncthreads();
        if (t == 0) {   // barrier among the NB extras only (all co-resident, low IDs)
            atomicAdd(ctr, 1);
            while (atomicAdd(ctr, 0) < NB) __builtin_amdgcn_s_sleep(16);
        }
        __syncthreads();
        // ---- scatter (grid-stride over the NB extras; overlaps MFMA blocks) ----
        for (int e = b * 256 + t; e < EE; e += NB * 256) {
            int src, dst;
            if (e < E) { src = ei[e]; dst = ei[E + e]; } else { src = dst = e - E; }
            int slot = atomicAdd(&woff[dst], 1);
            esrc[slot] = src;
        }
        return;
    }

    // ---- emb proj (K=64, KP=72) ----
    for (int i = t; i < 128 * 8; i += 256) {
        int row = i >> 3, c8 = i & 7;
        *(f16x8*)&w_lds[row * 72 + 8 * c8] = *(const f16x8*)&wt_emb[(size_t)row * 64 + 8 * c8];
    }
    int n0 = ((int)blockIdx.x - NB) * 64;
    for (int i = t; i < 64 * 8; i += 256) {
        int row = i >> 3, c8 = i & 7;
        f16x8 v = {};
        int n = n0 + row;
        if (n < N) {
            const float4* ptr = (const float4*)&x[(size_t)n * 64 + 8 * c8];
            float4 a = ptr[0], b4 = ptr[1];
            v[0] = (_Float16)a.x; v[1] = (_Float16)a.y;
            v[2] = (_Float16)a.z; v[3] = (_Float16)a.w;
            v[4] = (_Float16)b4.x; v[5] = (_Float16)b4.y;
            v[6] = (_Float16)b4.z; v[7] = (_Float16)b4.w;
        }
        *(f16x8*)&a_lds[row * 72 + 8 * c8] = v;
    }
    __syncthreads();

    int lane = t & 63, wv = t >> 6;
    int l15 = lane & 15, quad = lane >> 4;

    f32x4 acc[8];
#pragma unroll
    for (int c = 0; c < 8; ++c) acc[c] = (f32x4){0.f, 0.f, 0.f, 0.f};
#pragma unroll
    for (int kk = 0; kk < 2; ++kk) {
        f16x8 af = *(const f16x8*)&a_lds[(wv * 16 + l15) * 72 + kk * 32 + quad * 8];
#pragma unroll
        for (int c = 0; c < 8; ++c) {
            f16x8 bf = *(const f16x8*)&w_lds[(c * 16 + l15) * 72 + kk * 32 + quad * 8];
            acc[c] = __builtin_amdgcn_mfma_f32_16x16x32_f16(af, bf, acc[c], 0, 0, 0);
        }
    }
    float bv[8];
#pragma unroll
    for (int c = 0; c < 8; ++c) bv[c] = emb_b[c * 16 + l15];
    __syncthreads();
    // epilogue: h -> a_lds (stride 136); concurrently stage layer-0 W
#pragma unroll
    for (int r = 0; r < 4; ++r) {
        int n = n0 + wv * 16 + quad * 4 + r;
        int nt = (n < N) ? ntypes[n] : 0;
#pragma unroll
        for (int c = 0; c < 8; ++c)
            a_lds[(wv * 16 + quad * 4 + r) * 136 + c * 16 + l15] =
                (_Float16)(acc[c][r] + bv[c] + nemb[nt * HID + c * 16 + l15]);
    }
    for (int i = t; i < 128 * 16; i += 256) {
        int row = i >> 4, c8 = i & 15;
        *(f16x8*)&w_lds[row * 136 + 8 * c8] = *(const f16x8*)&wt_g0[(size_t)row * 128 + 8 * c8];
    }
    __syncthreads();
    // h16 global store (residual for agg0) + layer-0 MFMA
    for (int i = t; i < 64 * 16; i += 256) {
        int row = i >> 4, c8 = i & 15;
        int n = n0 + row;
        if (n < N) *(f16x8*)&h16[(size_t)n * HID + 8 * c8] = *(const f16x8*)&a_lds[row * 136 + 8 * c8];
    }
#pragma unroll
    for (int c = 0; c < 8; ++c) acc[c] = (f32x4){0.f, 0.f, 0.f, 0.f};
#pragma unroll
    for (int kk = 0; kk < 4; ++kk) {
        f16x8 af = *(const f16x8*)&a_lds[(wv * 16 + l15) * 136 + kk * 32 + quad * 8];
#pragma unroll
        for (int c = 0; c < 8; ++c) {
            f16x8 bf = *(const f16x8*)&w_lds[(c * 16 + l15) * 136 + kk * 32 + quad * 8];
            acc[c] = __builtin_amdgcn_mfma_f32_16x16x32_f16(af, bf, acc[c], 0, 0, 0);
        }
    }
    __syncthreads();
#pragma unroll
    for (int c = 0; c < 8; ++c)
#pragma unroll
        for (int r = 0; r < 4; ++r)
            a_lds[(wv * 16 + quad * 4 + r) * 136 + c * 16 + l15] = (_Float16)acc[c][r];
    __syncthreads();
    for (int i = t; i < 64 * 16; i += 256) {
        int row = i >> 4, c8 = i & 15;
        int n = n0 + row;
        if (n < N) *(f16x8*)&hp_out[(size_t)n * HID + 8 * c8] = *(const f16x8*)&a_lds[row * 136 + 8 * c8];
    }
    for (int task2 = t; task2 < 512; task2 += 256) {
        int row = task2 >> 3, hd = task2 & 7;
        int n = n0 + row;
        if (n >= N) continue;
        f16x8 v0 = *(const f16x8*)&a_lds[row * 136 + hd * 16];
        f16x8 v1 = *(const f16x8*)&a_lds[row * 136 + hd * 16 + 8];
        float va = 0.f, vd = 0.f;
#pragma unroll
        for (int j = 0; j < 8; ++j) {
            va += (float)v0[j] * asrc[hd * 16 + j] + (float)v1[j] * asrc[hd * 16 + 8 + j];
            vd += (float)v0[j] * adst[hd * 16 + j] + (float)v1[j] * adst[hd * 16 + 8 + j];
        }
        als_out[n * HEADS + hd] = va;
        ald_out[n * HEADS + hd] = vd;
    }
}

// ================= standalone MFMA projection (1 tile of 64 rows per block) ===========
// mode 1: GAT proj epilogue (hp16 store + als/ald via LDS transpose)
// mode 2: score epilogue (tanh MLP -> escore)
__global__ __launch_bounds__(256) void proj_kernel(
    int mode, const _Float16* __restrict__ A16, const _Float16* __restrict__ Wt,
    const float* __restrict__ asrc, const float* __restrict__ adst,
    _Float16* __restrict__ hp_out, float* __restrict__ als, float* __restrict__ ald,
    const float* __restrict__ b1, const float* __restrict__ w2, const float* __restrict__ b2,
    float* __restrict__ escore, int N)
{
    __shared__ _Float16 w_lds[128 * 136];
    __shared__ _Float16 a_lds[64 * 136];
    int t = threadIdx.x;

    for (int i = t; i < 128 * 16; i += 256) {
        int row = i >> 4, c8 = i & 15;
        *(f16x8*)&w_lds[row * 136 + 8 * c8] = *(const f16x8*)&Wt[(size_t)row * 128 + 8 * c8];
    }
    int n0 = blockIdx.x * 64;
    for (int i = t; i < 64 * 16; i += 256) {
        int row = i >> 4, c8 = i & 15;
        f16x8 v = {};
        if (n0 + row < N) v = *(const f16x8*)&A16[(size_t)(n0 + row) * HID + 8 * c8];
        *(f16x8*)&a_lds[row * 136 + 8 * c8] = v;
    }
    __syncthreads();

    int lane = t & 63, wv = t >> 6;
    int l15 = lane & 15, quad = lane >> 4;

    f32x4 acc[8];
#pragma unroll
    for (int c = 0; c < 8; ++c) acc[c] = (f32x4){0.f, 0.f, 0.f, 0.f};
#pragma unroll
    for (int kk = 0; kk < 4; ++kk) {
        f16x8 af = *(const f16x8*)&a_lds[(wv * 16 + l15) * 136 + kk * 32 + quad * 8];
#pragma unroll
        for (int c = 0; c < 8; ++c) {
            f16x8 bf = *(const f16x8*)&w_lds[(c * 16 + l15) * 136 + kk * 32 + quad * 8];
            acc[c] = __builtin_amdgcn_mfma_f32_16x16x32_f16(af, bf, acc[c], 0, 0, 0);
        }
    }

    if (mode == 1) {
        __syncthreads();
#pragma unroll
        for (int c = 0; c < 8; ++c)
#pragma unroll
            for (int r = 0; r < 4; ++r)
                a_lds[(wv * 16 + quad * 4 + r) * 136 + c * 16 + l15] = (_Float16)acc[c][r];
        __syncthreads();
        for (int i = t; i < 64 * 16; i += 256) {
            int row = i >> 4, c8 = i & 15;
            int n = n0 + row;
            if (n < N) *(f16x8*)&hp_out[(size_t)n * HID + 8 * c8] = *(const f16x8*)&a_lds[row * 136 + 8 * c8];
        }
        for (int task2 = t; task2 < 512; task2 += 256) {
            int row = task2 >> 3, hd = task2 & 7;
            int n = n0 + row;
            if (n >= N) continue;
            f16x8 v0 = *(const f16x8*)&a_lds[row * 136 + hd * 16];
            f16x8 v1 = *(const f16x8*)&a_lds[row * 136 + hd * 16 + 8];
            float va = 0.f, vd = 0.f;
#pragma unroll
            for (int j = 0; j < 8; ++j) {
                va += (float)v0[j] * asrc[hd * 16 + j] + (float)v1[j] * asrc[hd * 16 + 8 + j];
                vd += (float)v0[j] * adst[hd * 16 + j] + (float)v1[j] * adst[hd * 16 + 8 + j];
            }
            als[n * HEADS + hd] = va;
            ald[n * HEADS + hd] = vd;
        }
    } else {
        float b2v = b2[0];
        float treg[4] = {0.f, 0.f, 0.f, 0.f};
#pragma unroll
        for (int c = 0; c < 8; ++c) {
            float b1v = b1[c * 16 + l15];
            float w2v = w2[c * 16 + l15];
#pragma unroll
            for (int r = 0; r < 4; ++r)
                treg[r] += fast_tanh(acc[c][r] + b1v) * w2v;
        }
#pragma unroll
        for (int r = 0; r < 4; ++r) {
            float v = treg[r];
#pragma unroll
            for (int m = 8; m >= 1; m >>= 1) v += __shfl_xor(v, m, 64);
            if (l15 == 0) {
                int n = n0 + wv * 16 + quad * 4 + r;
                if (n < N) escore[n] = __expf(v + b2v);
            }
        }
    }
}

// ================= fused aggregate (R2-verified): wave per node, 16 edges in flight ====
__global__ void gat_aggregate_kernel(const int* __restrict__ rowptr, const int* __restrict__ esrc,
                                     const float* __restrict__ als, const float* __restrict__ ald,
                                     const _Float16* __restrict__ hp16, const float* __restrict__ gb,
                                     const float* __restrict__ lg, const float* __restrict__ lb,
                                     _Float16* __restrict__ h16, int N) {
    int wave = threadIdx.x >> 6;
    int lane = threadIdx.x & 63;
    int n = blockIdx.x * 4 + wave;
    if (n >= N) return;
    int esub = lane >> 4;
    int cg = lane & 15;
    int hd = cg >> 1;
    float adv = ald[n * HEADS + hd];
    int row = rowptr[n], end = rowptr[n + 1];
    int last = end - 1;
    float acc[8] = {0.f, 0.f, 0.f, 0.f, 0.f, 0.f, 0.f, 0.f};
    float sw = 0.f;
    for (int base = row; base < end; base += 16) {
        int iA = base + esub;
        int iB = iA + 4, iC = iA + 8, iD = iA + 12;
        int cA = iA <= last ? iA : last;
        int cB = iB <= last ? iB : last;
        int cC = iC <= last ? iC : last;
        int cD = iD <= last ? iD : last;
        int sA = esrc[cA], sB = esrc[cB], sC = esrc[cC], sD = esrc[cD];
        f16x8 pA = *(const f16x8*)&hp16[(size_t)sA * HID + cg * 8];
        f16x8 pB = *(const f16x8*)&hp16[(size_t)sB * HID + cg * 8];
        f16x8 pC = *(const f16x8*)&hp16[(size_t)sC * HID + cg * 8];
        f16x8 pD = *(const f16x8*)&hp16[(size_t)sD * HID + cg * 8];
        float aA = als[sA * HEADS + hd];
        float aB = als[sB * HEADS + hd];
        float aC = als[sC * HEADS + hd];
        float aD = als[sD * HEADS + hd];
        float lA = aA + adv; lA = lA > 0.f ? lA : 0.2f * lA;
        float lB = aB + adv; lB = lB > 0.f ? lB : 0.2f * lB;
        float lC = aC + adv; lC = lC > 0.f ? lC : 0.2f * lC;
        float lD = aD + adv; lD = lD > 0.f ? lD : 0.2f * lD;
        float wA = __expf(lA) * ((iA < end) ? 1.f : 0.f);
        float wB = __expf(lB) * ((iB < end) ? 1.f : 0.f);
        float wC = __expf(lC) * ((iC < end) ? 1.f : 0.f);
        float wD = __expf(lD) * ((iD < end) ? 1.f : 0.f);
        sw += (wA + wB) + (wC + wD);
#ifdef HAVE_FDOT2
        f16x2 wAB; wAB[0] = (_Float16)wA; wAB[1] = (_Float16)wB;
        f16x2 wCD; wCD[0] = (_Float16)wC; wCD[1] = (_Float16)wD;
#pragma unroll
        for (int j = 0; j < 8; ++j) {
            f16x2 prAB; prAB[0] = pA[j]; prAB[1] = pB[j];
            f16x2 prCD; prCD[0] = pC[j]; prCD[1] = pD[j];
            acc[j] = __builtin_amdgcn_fdot2(prAB, wAB, acc[j], false);
            acc[j] = __builtin_amdgcn_fdot2(prCD, wCD, acc[j], false);
        }
#else
#pragma unroll
        for (int j = 0; j < 8; ++j)
            acc[j] += wA * (float)pA[j] + wB * (float)pB[j]
                    + wC * (float)pC[j] + wD * (float)pD[j];
#endif
    }
#pragma unroll
    for (int m = 16; m <= 32; m <<= 1) {
        sw += __shfl_xor(sw, m, 64);
#pragma unroll
        for (int j = 0; j < 8; ++j) acc[j] += __shfl_xor(acc[j], m, 64);
    }
    float inv_sw = 1.f / sw;
    float4 g0 = ((const float4*)(gb + cg * 8))[0];
    float4 g1 = ((const float4*)(gb + cg * 8))[1];
    float v[8];
    v[0] = acc[0] * inv_sw + g0.x; v[1] = acc[1] * inv_sw + g0.y;
    v[2] = acc[2] * inv_sw + g0.z; v[3] = acc[3] * inv_sw + g0.w;
    v[4] = acc[4] * inv_sw + g1.x; v[5] = acc[5] * inv_sw + g1.y;
    v[6] = acc[6] * inv_sw + g1.z; v[7] = acc[7] * inv_sw + g1.w;
    float s = 0.f;
#pragma unroll
    for (int j = 0; j < 8; ++j) s += v[j];
#pragma unroll
    for (int m = 32; m >= 1; m >>= 1) s += __shfl_xor(s, m, 64);
    float mu = s * (1.f / 512.f);
    float d[8], sq = 0.f;
#pragma unroll
    for (int j = 0; j < 8; ++j) { d[j] = v[j] - mu; sq += d[j] * d[j]; }
#pragma unroll
    for (int m = 32; m >= 1; m >>= 1) sq += __shfl_xor(sq, m, 64);
    float inv = rsqrtf(sq * (1.f / 512.f) + 1e-5f);
    float4 lg0 = ((const float4*)(lg + cg * 8))[0];
    float4 lg1 = ((const float4*)(lg + cg * 8))[1];
    float4 lb0 = ((const float4*)(lb + cg * 8))[0];
    float4 lb1 = ((const float4*)(lb + cg * 8))[1];
    float lgv[8] = {lg0.x, lg0.y, lg0.z, lg0.w, lg1.x, lg1.y, lg1.z, lg1.w};
    float lbv[8] = {lb0.x, lb0.y, lb0.z, lb0.w, lb1.x, lb1.y, lb1.z, lb1.w};
    f16x8 hold = *(const f16x8*)&h16[(size_t)n * HID + cg * 8];
    f16x8 hnew;
#pragma unroll
    for (int j = 0; j < 8; ++j) {
        float r = d[j] * inv * lgv[j] + lbv[j] + (float)hold[j];
        hnew[j] = (_Float16)(r > 0.f ? r : 0.f);
    }
    if (esub == 0) *(f16x8*)&h16[(size_t)n * HID + cg * 8] = hnew;
}

// ================= per-graph pooling (R2-verified, 512 threads) =================
__global__ void pool_graph_kernel(const _Float16* __restrict__ h16, const float* __restrict__ escore,
                                  const int* __restrict__ gstart, float* __restrict__ sums,
                                  float* __restrict__ cnts, float* __restrict__ hgZ, int G) {
    int g = blockIdx.x;
    int t = threadIdx.x;               // 0..511
    int c = t & 127, grp = t >> 7;     // 4 groups
    int s = gstart[g], e = gstart[g + 1];
    float msum = 0.f, asum = 0.f, z = 0.f;
    for (int n = s + grp; n < e; n += 4) {
        float hv = (float)h16[(size_t)n * HID + c];
        float es = escore[n];
        msum += hv;
        asum += es * hv;
        if (c == 0) z += es;
    }
    __shared__ float sm[4][HID];
    __shared__ float sa[4][HID];
    __shared__ float sz[4];
    sm[grp][c] = msum;
    sa[grp][c] = asum;
    if (c == 0) sz[grp] = z;
    __syncthreads();
    if (t < HID) {
        float m = sm[0][t] + sm[1][t] + sm[2][t] + sm[3][t];
        float a = sa[0][t] + sa[1][t] + sa[2][t] + sa[3][t];
        sums[(size_t)g * HID + t] = m;
        atomicAdd(&hgZ[t], a);
    } else if (t == HID) {
        cnts[g] = (float)(e - s);
        atomicAdd(&hgZ[HID], sz[0] + sz[1] + sz[2] + sz[3]);
    }
}

// ================= classifier head (R2-verified) =================
__global__ void head_kernel(const float* __restrict__ hgZ, const float* __restrict__ sums,
                            const float* __restrict__ cnts, const float* __restrict__ W1,
                            const float* __restrict__ b1, const float* __restrict__ W2,
                            const float* __restrict__ b2, float* __restrict__ out, int G) {
    int g = blockIdx.x;
    int t = threadIdx.x;
    __shared__ float hr[HID];
    __shared__ float part[2];
    float Z = hgZ[HID];
    float cnt = cnts[g];
    cnt = cnt > 1.f ? cnt : 1.f;
    hr[t] = hgZ[t] / Z + sums[(size_t)g * HID + t] / cnt;
    __syncthreads();
    float acc = b1[t];
#pragma unroll 8
    for (int k = 0; k < HID; ++k) acc += hr[k] * W1[k * HID + t];
    acc = acc > 0.f ? acc : 0.f;
    float v = acc * W2[t];
#pragma unroll
    for (int m = 32; m >= 1; m >>= 1) v += __shfl_xor(v, m, 64);
    if ((t & 63) == 0) part[t >> 6] = v;
    __syncthreads();
    if (t == 0) out[g] = part[0] + part[1] + b2[0];
}

extern "C" void kernel_launch(void* const* d_in, const int* in_sizes, int n_in,
                              void* d_out, int out_size, void* d_ws, size_t ws_size,
                              hipStream_t stream) {
    const float* x        = (const float*)d_in[0];
    const int*   ei       = (const int*)d_in[1];
    const int*   ntypes   = (const int*)d_in[2];
    const int*   batch    = (const int*)d_in[3];
    const float* emb_W    = (const float*)d_in[4];
    const float* emb_b    = (const float*)d_in[5];
    const float* nemb     = (const float*)d_in[6];
    const float* gat_W    = (const float*)d_in[7];
    const float* att_src  = (const float*)d_in[8];
    const float* att_dst  = (const float*)d_in[9];
    const float* gat_b    = (const float*)d_in[10];
    const float* ln_g     = (const float*)d_in[11];
    const float* ln_b     = (const float*)d_in[12];
    const float* ga_W1    = (const float*)d_in[13];
    const float* ga_b1    = (const float*)d_in[14];
    const float* ga_W2    = (const float*)d_in[15];
    const float* ga_b2    = (const float*)d_in[16];
    const float* cls_W1   = (const float*)d_in[17];
    const float* cls_b1   = (const float*)d_in[18];
    const float* cls_W2   = (const float*)d_in[19];
    const float* cls_b2   = (const float*)d_in[20];
    float* out = (float*)d_out;

    const int N  = in_sizes[2];
    const int E  = in_sizes[1] / 2;
    const int EE = E + N;
    const int G  = out_size;
    const int NB = (N + 255) / 256;

    // ---- workspace layout ----
    float* ws      = (float*)d_ws;
    float* als     = ws;                               // N*8
    float* ald     = als + (size_t)N * HEADS;          // N*8
    float* escore  = ald + (size_t)N * HEADS;          // N
    float* sums    = escore + N;                       // G*128
    float* cnts    = sums + (size_t)G * HID;           // G
    float* hgZ     = cnts + G;                         // 136 (129 used)
    _Float16* h16  = (_Float16*)(hgZ + 136);           // N*128 (16B-aligned)
    _Float16* hp16 = h16 + (size_t)N * HID;            // N*128
    _Float16* wt_emb = hp16 + (size_t)N * HID;         // 128*64
    _Float16* wt_gat = wt_emb + 128 * 64;              // 3*128*128
    _Float16* wt_ga1 = wt_gat + 3 * 128 * 128;         // 128*128
    int*   rowptr  = (int*)(wt_ga1 + 128 * 128);       // N+1
    int*   woff    = rowptr + (N + 1);                 // N
    int*   deg     = woff + N;                         // N
    int*   ctr     = deg + N;                          // 1
    int*   esrc    = ctr + 1;                          // EE
    int*   gstart  = esrc + EE;                        // G+1

    int P1TOT = EE;
    if (P1TOT < 100000 + G + 1) P1TOT = 100000 + G + 1;

    // D1: zero deg + ctr (contiguous)
    hipMemsetAsync(deg, 0, ((size_t)N + 1) * sizeof(int), stream);
    // D2: prologue
    prologue_kernel<<<(P1TOT + 255) / 256, 256, 0, stream>>>(
        ei, deg, emb_W, gat_W, ga_W1, wt_emb, wt_gat, wt_ga1,
        batch, gstart, hgZ, E, EE, N, G);

    const int PB = (N + 63) / 64;   // 1 tile of 64 rows per block

    // D3: FK = CSR extras (blocks 0..NB-1) + emb/l0 proj (blocks NB..NB+PB-1)
    emb_l0_kernel<<<NB + PB, 256, 0, stream>>>(
        x, wt_emb, emb_b, nemb, ntypes, h16,
        wt_gat, att_src, att_dst, hp16, als, ald,
        ei, deg, rowptr, woff, esrc, ctr, N, E, EE, NB);

    // D4..D8: agg / proj alternation
    gat_aggregate_kernel<<<(N + 3) / 4, 256, 0, stream>>>(
        rowptr, esrc, als, ald, hp16,
        gat_b, ln_g, ln_b, h16, N);

    for (int l = 1; l < 3; ++l) {
        proj_kernel<<<PB, 256, 0, stream>>>(
            1, h16, wt_gat + (size_t)l * HID * HID,
            att_src + l * HID, att_dst + l * HID,
            hp16, als, ald, nullptr, nullptr, nullptr, nullptr, N);
        gat_aggregate_kernel<<<(N + 3) / 4, 256, 0, stream>>>(
            rowptr, esrc, als, ald, hp16,
            gat_b + l * HID, ln_g + l * HID, ln_b + l * HID, h16, N);
    }

    // D9: score projection
    proj_kernel<<<PB, 256, 0, stream>>>(
        2, h16, wt_ga1, nullptr, nullptr,
        nullptr, nullptr, nullptr,
        ga_b1, ga_W2, ga_b2, escore, N);

    // D10/D11: pooling + head
    pool_graph_kernel<<<G, 512, 0, stream>>>(h16, escore, gstart, sums, cnts, hgZ, G);
    head_kernel<<<G, 128, 0, stream>>>(hgZ, sums, cnts, cls_W1, cls_b1, cls_W2, cls_b2, out, G);
}